// Round 12
// baseline (2158.432 us; speedup 1.0000x reference)
//
#include <hip/hip_runtime.h>

#define NN 50000
#define NE 800000
#define TT 12
#define NBIN (4 * NN)
#define NBLK ((NBIN + 255) / 256)
#define EHALF (NE / 2)

typedef _Float16 h16;
typedef __attribute__((ext_vector_type(2))) _Float16 h16x2;
typedef __attribute__((ext_vector_type(4))) _Float16 h16x4;
typedef __attribute__((ext_vector_type(8))) _Float16 half8;
typedef __attribute__((ext_vector_type(4))) float f32x4;
typedef __attribute__((address_space(3))) h16 as3h16;
typedef __attribute__((address_space(3))) half8 as3half8;

static constexpr size_t alignup(size_t x) { return (x + 255) & ~(size_t)255; }
// workspace layout (float units)
static constexpr size_t O_CNT  = 0;                                   // (NBIN+1) ints
static constexpr size_t O_CUR  = alignup(O_CNT + NBIN + 1);           // NBIN ints (dead; layout kept)
static constexpr size_t O_DEGO = alignup(O_CUR + NBIN);               // NN f
static constexpr size_t O_BSUM = alignup(O_DEGO + NN);                // 1024 ints
static constexpr size_t O_BEXC = O_BSUM + 1024;                       // 1024 ints
static constexpr size_t O_EDG  = alignup(O_BEXC + 1024);              // NE uint2 {src, no|ni h16x2}
static constexpr size_t O_TXX  = alignup(O_EDG + (size_t)NE * 2);     // [T][NN][4] f32 (first NE ints reused as rank[] between k_hist and k_scatter)
static constexpr size_t O_WF1ZR= alignup(O_TXX + (size_t)TT * NN * 4);// 12288 f
static constexpr size_t O_WF1H = alignup(O_WF1ZR + 12288);            // 6144 f
static constexpr size_t O_WF2ZR= alignup(O_WF1H + 6144);              // 24576 f
static constexpr size_t O_WF2H = alignup(O_WF2ZR + 24576);            // 12288 f
static constexpr size_t O_WX1ZR= alignup(O_WF2H + 12288);             // 768 f
static constexpr size_t O_WX1H = alignup(O_WX1ZR + 768);              // 384 f
// interleaved pair state buffers: rows of 128 h16 = [partA(64) | partB(64)]
static constexpr size_t O_PX0  = alignup(O_WX1H + 384);               // pairX even: [h1(t) | h2(t-1)], t even
static constexpr size_t O_PX1  = O_PX0 + (size_t)NN * 64;             // pairX odd
static constexpr size_t O_PZR  = O_PX1 + (size_t)NN * 64;             // [rhh1 | rhh2]
static constexpr size_t O_Z1   = O_PZR + (size_t)NN * 64;             // z1 h16 (stride 64)
static constexpr size_t O_Z2   = O_Z1 + (size_t)NN * 32;              // z2 h16
static constexpr size_t O_TXA  = alignup(O_Z2 + (size_t)NN * 32);     // NN*128 h16
static constexpr size_t O_TXB  = alignup(O_TXA + (size_t)NN * 64);    // NN*256 h16
static constexpr size_t WS_FLOATS = O_TXB + (size_t)NN * 128;

__device__ __forceinline__ float sigm_(float x) { return 1.f / (1.f + __expf(-x)); }
__device__ __forceinline__ float tanh_(float x) { float e = __expf(2.f * x); return 1.f - 2.f / (e + 1.f); }

__device__ __forceinline__ void gld_lds16(const h16* g, as3h16* l) {
    __builtin_amdgcn_global_load_lds(
        (const __attribute__((address_space(1))) void*)g,
        (__attribute__((address_space(3))) void*)l, 16, 0, 0);
}

template <int N>
__device__ __forceinline__ void wait_lgkm0_vm() {
    if constexpr (N == 0)      asm volatile("s_waitcnt lgkmcnt(0) vmcnt(0)" ::: "memory");
    else if constexpr (N == 1) asm volatile("s_waitcnt lgkmcnt(0) vmcnt(1)" ::: "memory");
    else                       asm volatile("s_waitcnt lgkmcnt(0) vmcnt(2)" ::: "memory");
}

// ---------------- preprocessing ----------------

// zero: counters + pEven only (txB/pOdd/txA zeroing is dead: t=0 L1 is closed-form and the
// prologue aggP fully writes txB before first read).
__global__ __launch_bounds__(256) void k_zero(float* ws) {
    size_t i = (size_t)blockIdx.x * 256 + threadIdx.x;
    size_t stride = (size_t)gridDim.x * 256;
    for (size_t p = i; p < O_BSUM + 2048; p += stride) ((int*)ws)[p] = 0;
    for (size_t p = i; p < (size_t)NN * 64; p += stride) ws[O_PX0 + p] = 0.f; // pEven (h2(-1)=0; partA overwritten by k_l1h0)
}

// bin = dest*4 + src_quarter; single scattered atomic per edge, rank stored for atomic-free
// scatter. Half-range split keeps these below the steady-loop kernels in the top-5.
__global__ __launch_bounds__(256) void k_hist(const int* ei, float* ws, int ebase) {
    int e = ebase + blockIdx.x * 256 + threadIdx.x;
    if (e >= NE || e >= ebase + EHALF) return;
    int r = ei[e], c = ei[NE + e];
    int bin = c * 4 + r / 12500;
    int rk = atomicAdd((int*)ws + O_CNT + bin, 1);
    ((int*)ws)[O_TXX + e] = rk; // coalesced; O_TXX not live until k_aggx (which overwrites it fully)
}

__global__ __launch_bounds__(256) void k_scanA(float* ws) {
    __shared__ int sh[256];
    int t = threadIdx.x, i = blockIdx.x * 256 + t;
    int v = (i < NBIN) ? ((int*)ws)[O_CNT + i] : 0;
    sh[t] = v; __syncthreads();
    for (int o = 128; o > 0; o >>= 1) { if (t < o) sh[t] += sh[t + o]; __syncthreads(); }
    if (t == 0) ((int*)ws)[O_BSUM + blockIdx.x] = sh[0];
}

__global__ __launch_bounds__(256) void k_scanB(float* ws) {
    __shared__ int tot[256];
    int t = threadIdx.x;
    int* bsum = (int*)ws + O_BSUM;
    int* bexc = (int*)ws + O_BEXC;
    int base = t * 4;
    int v0 = (base + 0 < NBLK) ? bsum[base + 0] : 0;
    int v1 = (base + 1 < NBLK) ? bsum[base + 1] : 0;
    int v2 = (base + 2 < NBLK) ? bsum[base + 2] : 0;
    int v3 = (base + 3 < NBLK) ? bsum[base + 3] : 0;
    int sum = v0 + v1 + v2 + v3;
    tot[t] = sum; __syncthreads();
    for (int o = 1; o < 256; o <<= 1) {
        int a = (t >= o) ? tot[t - o] : 0;
        __syncthreads(); tot[t] += a; __syncthreads();
    }
    int excl = tot[t] - sum;
    if (base + 0 < NBLK) bexc[base + 0] = excl;
    if (base + 1 < NBLK) bexc[base + 1] = excl + v0;
    if (base + 2 < NBLK) bexc[base + 2] = excl + v0 + v1;
    if (base + 3 < NBLK) bexc[base + 3] = excl + v0 + v1 + v2;
    if (t == 255) ((int*)ws)[O_CNT + NBIN] = tot[255];
}

__global__ __launch_bounds__(256) void k_scanC(float* ws) {
    __shared__ int sh[256];
    int t = threadIdx.x, b = blockIdx.x, i = b * 256 + t;
    int v = (i < NBIN) ? ((int*)ws)[O_CNT + i] : 0;
    sh[t] = v; __syncthreads();
    for (int o = 1; o < 256; o <<= 1) {
        int a = (t >= o) ? sh[t - o] : 0;
        __syncthreads(); sh[t] += a; __syncthreads();
    }
    if (i < NBIN) ((int*)ws)[O_CNT + i] = ((int*)ws)[O_BEXC + b] + sh[t] - v;
}

// slot = offs[bin] + precomputed rank (no atomic); dego atomic lives here. Half-range split.
__global__ __launch_bounds__(256) void k_scatter(const int* ei, const float* ew, float* ws, int ebase) {
    int e = ebase + blockIdx.x * 256 + threadIdx.x;
    if (e >= NE || e >= ebase + EHALF) return;
    int r = ei[e], c = ei[NE + e];
    float w = ew[e];
    atomicAdd(ws + O_DEGO + r, w);
    int bin = c * 4 + r / 12500;
    int p = ((const int*)ws)[O_CNT + bin] + ((const int*)ws)[O_TXX + e];
    uint2 rec; rec.x = (unsigned)r; rec.y = __float_as_uint(w);
    ((uint2*)(ws + O_EDG))[p] = rec;
}

// per-node: deg_in = segment sum of w; rewrite records {src, (no,ni) h16x2}
__global__ __launch_bounds__(256) void k_norm(float* ws) {
    int n = blockIdx.x * 4 + (threadIdx.x >> 6);
    int lane = threadIdx.x & 63;
    const int* offs = (const int*)ws + O_CNT;
    uint2* recs = (uint2*)(ws + O_EDG);
    const float* dego = ws + O_DEGO;
    int e0 = offs[4 * n], e1 = offs[4 * n + 4];
    float s = 0.f;
    for (int e = e0 + lane; e < e1; e += 64) s += __uint_as_float(recs[e].y);
    #pragma unroll
    for (int m = 1; m < 64; m <<= 1) s += __shfl_xor(s, m);
    float inv = 1.f / s;
    for (int e = e0 + lane; e < e1; e += 64) {
        uint2 r = recs[e];
        float w = __uint_as_float(r.y);
        h16x2 nv; nv.x = (h16)(w / dego[r.x]); nv.y = (h16)(w * inv);
        r.y = __builtin_bit_cast(unsigned int, nv);
        recs[e] = r;
    }
}

// x aggregation for ALL timesteps, 2 nodes/wave: txx[t][n][c]
__global__ __launch_bounds__(256) void k_aggx(const float* __restrict__ x, float* __restrict__ ws) {
    int tid = threadIdx.x;
    int n = blockIdx.x * 8 + (tid >> 5);
    int l = tid & 31;
    const int* offs = (const int*)ws + O_CNT;
    const uint2* recs = (const uint2*)(ws + O_EDG);
    int e0 = offs[4 * n], e1 = offs[4 * n + 4];
    int f = l / 12, tt2 = l % 12;
    bool act = l < 24;
    float ao = 0.f, ai = 0.f;
    uint2 rc0, rc1;
    if (e0 < e1) {
        rc0 = recs[e0];
        rc1 = recs[(e0 + 1 < e1) ? e0 + 1 : e1 - 1];
    }
    for (int e = e0; e < e1; e += 2) {
        uint2 c0 = rc0, c1 = rc1;
        int n2 = (e + 2 < e1) ? e + 2 : e1 - 1, n3 = (e + 3 < e1) ? e + 3 : e1 - 1;
        rc0 = recs[n2]; rc1 = recs[n3];
        h16x2 nv0 = __builtin_bit_cast(h16x2, c0.y);
        h16x2 nv1 = __builtin_bit_cast(h16x2, c1.y);
        bool ok1 = (e + 1 < e1);
        float no1 = ok1 ? (float)nv1.x : 0.f, ni1 = ok1 ? (float)nv1.y : 0.f;
        if (act) {
            float v0 = x[(size_t)c0.x * 24 + f * 12 + tt2];
            float v1 = x[(size_t)c1.x * 24 + f * 12 + tt2];
            ao += (float)nv0.x * v0 + no1 * v1;
            ai += (float)nv0.y * v0 + ni1 * v1;
        }
    }
    if (act) {
        ws[O_TXX + ((size_t)tt2 * NN + n) * 4 + f] = ao;
        ws[O_TXX + ((size_t)tt2 * NN + n) * 4 + 2 + f] = ai;
    }
}

// ---------------- weight packing ----------------
__device__ void packf_dev(int L, int NO, const float* wa, const float* wb, h16* Wf, int idx) {
    int C = (L == 1) ? 66 : 128;
    int NT = NO / 16;
    int j = idx & 7, l = (idx >> 3) & 63;
    int rest = idx >> 9;
    int ct = rest % NT, ks = rest / NT;
    int k = ks * 32 + ((l >> 4) << 3) + j;
    int col = ct * 16 + (l & 15);
    const float* w = wa; int jj = col;
    if (NO == 128 && col >= 64) { w = wb; jj = col - 64; }
    int G = k >> 6, c6 = k & 63, sg, crow;
    if (L == 1) { sg = G; crow = 2 + c6; }
    else        { sg = G >> 1; crow = ((G & 1) << 6) + c6; }
    float v;
    if (sg == 0)      v = w[(size_t)(0 * C + crow) * 64 + jj] + w[(size_t)(2 * C + crow) * 64 + jj];
    else if (sg == 1) v = w[(size_t)(1 * C + crow) * 64 + jj];
    else              v = w[(size_t)(3 * C + crow) * 64 + jj];
    Wf[idx] = (h16)v;
}

__device__ void packx_dev(int NO, const float* wa, const float* wb, float* Wx, int idx) {
    if (idx >= 6 * NO) return;
    int cc = idx / NO, col = idx % NO;
    const float* w = wa; int jj = col;
    if (NO == 128 && col >= 64) { w = wb; jj = col - 64; }
    int sg = cc >> 1, c = cc & 1;
    float v;
    if (sg == 0)      v = w[(size_t)(0 * 66 + c) * 64 + jj] + w[(size_t)(2 * 66 + c) * 64 + jj];
    else if (sg == 1) v = w[(size_t)(1 * 66 + c) * 64 + jj];
    else              v = w[(size_t)(3 * 66 + c) * 64 + jj];
    Wx[idx] = v;
}

__global__ __launch_bounds__(256) void k_packall(const float* w1z, const float* w1r, const float* w1h,
    const float* w2z, const float* w2r, const float* w2h, float* ws) {
    int b = blockIdx.x, t = threadIdx.x;
    if (b < 96)       packf_dev(1, 128, w1z, w1r, (h16*)(ws + O_WF1ZR), b * 256 + t);
    else if (b < 144) packf_dev(1, 64,  w1h, nullptr, (h16*)(ws + O_WF1H), (b - 96) * 256 + t);
    else if (b < 336) packf_dev(2, 128, w2z, w2r, (h16*)(ws + O_WF2ZR), (b - 144) * 256 + t);
    else if (b < 432) packf_dev(2, 64,  w2h, nullptr, (h16*)(ws + O_WF2H), (b - 336) * 256 + t);
    else {
        int idx = (b - 432) * 256 + t;
        if (idx < 768) packx_dev(128, w1z, w1r, ws + O_WX1ZR, idx);
        int idx2 = idx - 768;
        if (idx2 >= 0 && idx2 < 384) packx_dev(64, w1h, nullptr, ws + O_WX1H, idx2);
    }
}

// ---------------- t=0 closed-form prologue (A-operands identically zero at t=0) ----------------
__global__ __launch_bounds__(256) void k_l1zr0(const float* __restrict__ x, const float* __restrict__ txx,
    const float* __restrict__ wx, const float* __restrict__ bz, float* ws) {
    int tid = threadIdx.x;
    int n = blockIdx.x * 4 + (tid >> 6), col = tid & 63;
    float xa0 = x[(size_t)n * 24], xa1 = x[(size_t)n * 24 + 12];
    float4 tg = *(const float4*)&txx[(size_t)n * 4];
    float v = bz[col] + xa0 * wx[col] + xa1 * wx[128 + col] + tg.x * wx[256 + col]
            + tg.y * wx[384 + col] + tg.z * wx[512 + col] + tg.w * wx[640 + col];
    ((h16*)(ws + O_Z1))[(size_t)n * 64 + col] = (h16)sigm_(v);
}

__global__ __launch_bounds__(256) void k_l1h0(const float* __restrict__ x, const float* __restrict__ txx,
    const float* __restrict__ wx, const float* __restrict__ bh, float* ws) {
    int tid = threadIdx.x;
    int n = blockIdx.x * 4 + (tid >> 6), col = tid & 63;
    float xa0 = x[(size_t)n * 24], xa1 = x[(size_t)n * 24 + 12];
    float4 tg = *(const float4*)&txx[(size_t)n * 4];
    float v = bh[col] + xa0 * wx[col] + xa1 * wx[64 + col] + tg.x * wx[128 + col]
            + tg.y * wx[192 + col] + tg.z * wx[256 + col] + tg.w * wx[320 + col];
    float z = (float)((const h16*)(ws + O_Z1))[(size_t)n * 64 + col];
    float hn = fmaxf((1.f - z) * tanh_(v), 0.f);
    ((h16*)(ws + O_PX0))[(size_t)n * 128 + col] = (h16)hn;
}

// ---- dual gather over interleaved pair table: 4 nodes/wave, 16 lanes x 16B = 256B row, 4-edge unroll ----
__global__ __launch_bounds__(256) void k_aggP(
    const h16* __restrict__ T,
    h16* __restrict__ outA, int orsA, int oA, int iA,
    h16* __restrict__ outB, int orsB, int oB, int iB,
    const float* __restrict__ ws) {
    int tid = threadIdx.x, lane = tid & 63, wv = tid >> 6;
    int q = lane >> 4, fl = lane & 15;
    int n = blockIdx.x * 16 + wv * 4 + q;
    const int* offs = (const int*)ws + O_CNT;
    const uint2* recs = (const uint2*)(ws + O_EDG);
    int e0 = offs[4 * n], e1 = offs[4 * n + 4];
    float ao[8] = {}, ai[8] = {};
    for (int e = e0; e < e1; e += 4) {
        int i1 = e + 1 < e1 ? e + 1 : e1 - 1;
        int i2 = e + 2 < e1 ? e + 2 : e1 - 1;
        int i3 = e + 3 < e1 ? e + 3 : e1 - 1;
        uint2 r0 = recs[e], r1 = recs[i1], r2 = recs[i2], r3 = recs[i3];
        half8 v0 = *(const half8*)(T + (size_t)r0.x * 128 + fl * 8);
        half8 v1 = *(const half8*)(T + (size_t)r1.x * 128 + fl * 8);
        half8 v2 = *(const half8*)(T + (size_t)r2.x * 128 + fl * 8);
        half8 v3 = *(const half8*)(T + (size_t)r3.x * 128 + fl * 8);
        h16x2 m0 = __builtin_bit_cast(h16x2, r0.y);
        h16x2 m1 = __builtin_bit_cast(h16x2, r1.y);
        h16x2 m2 = __builtin_bit_cast(h16x2, r2.y);
        h16x2 m3 = __builtin_bit_cast(h16x2, r3.y);
        float no0 = (float)m0.x, ni0 = (float)m0.y;
        float no1 = (e + 1 < e1) ? (float)m1.x : 0.f, ni1 = (e + 1 < e1) ? (float)m1.y : 0.f;
        float no2 = (e + 2 < e1) ? (float)m2.x : 0.f, ni2 = (e + 2 < e1) ? (float)m2.y : 0.f;
        float no3 = (e + 3 < e1) ? (float)m3.x : 0.f, ni3 = (e + 3 < e1) ? (float)m3.y : 0.f;
        #pragma unroll
        for (int j = 0; j < 8; ++j) {
            float f0 = (float)v0[j], f1 = (float)v1[j], f2 = (float)v2[j], f3 = (float)v3[j];
            ao[j] += no0 * f0 + no1 * f1 + no2 * f2 + no3 * f3;
            ai[j] += ni0 * f0 + ni1 * f1 + ni2 * f2 + ni3 * f3;
        }
    }
    h16* outP = (fl < 8) ? outA : outB;
    int ors = (fl < 8) ? orsA : orsB;
    int fo = (fl < 8) ? fl : fl - 8;
    int oT = ((fl < 8) ? oA : oB) + fo * 8;
    int iT = ((fl < 8) ? iA : iB) + fo * 8;
    half8 wo, wi;
    #pragma unroll
    for (int j = 0; j < 8; ++j) { wo[j] = (h16)ao[j]; wi[j] = (h16)ai[j]; }
    *(half8*)(outP + (size_t)n * ors + oT) = wo;
    *(half8*)(outP + (size_t)n * ors + iT) = wi;
}

// ---- single-table gather (stride hs rows): 8 nodes/wave, 8 lanes x 16B ----
__global__ __launch_bounds__(256) void k_agg1(
    const h16* __restrict__ T, int hs,
    h16* __restrict__ out, int ors, int oA, int iA,
    const float* __restrict__ ws) {
    int tid = threadIdx.x, lane = tid & 63, wv = tid >> 6;
    int q = lane >> 3, fl = lane & 7;
    int n = blockIdx.x * 32 + wv * 8 + q;
    if (n >= NN) n = NN - 1;
    const int* offs = (const int*)ws + O_CNT;
    const uint2* recs = (const uint2*)(ws + O_EDG);
    int e0 = offs[4 * n], e1 = offs[4 * n + 4];
    float ao[8] = {}, ai[8] = {};
    for (int e = e0; e < e1; e += 2) {
        int i1 = e + 1 < e1 ? e + 1 : e1 - 1;
        uint2 r0 = recs[e], r1 = recs[i1];
        half8 v0 = *(const half8*)(T + (size_t)r0.x * hs + fl * 8);
        half8 v1 = *(const half8*)(T + (size_t)r1.x * hs + fl * 8);
        h16x2 m0 = __builtin_bit_cast(h16x2, r0.y);
        h16x2 m1 = __builtin_bit_cast(h16x2, r1.y);
        float no0 = (float)m0.x, ni0 = (float)m0.y;
        float no1 = (e + 1 < e1) ? (float)m1.x : 0.f, ni1 = (e + 1 < e1) ? (float)m1.y : 0.f;
        #pragma unroll
        for (int j = 0; j < 8; ++j) {
            float f0 = (float)v0[j], f1 = (float)v1[j];
            ao[j] += no0 * f0 + no1 * f1;
            ai[j] += ni0 * f0 + ni1 * f1;
        }
    }
    half8 wo, wi;
    #pragma unroll
    for (int j = 0; j < 8; ++j) { wo[j] = (h16)ao[j]; wi[j] = (h16)ai[j]; }
    *(half8*)(out + (size_t)n * ors + oA + fl * 8) = wo;
    *(half8*)(out + (size_t)n * ors + iA + fl * 8) = wi;
}

// ---------------- MFMA dconv GEMM: 4-wave (256t) blocks, 32-row tiles, 4-slot pipelined LDS A ----------------
// __launch_bounds__(256, 8): cap VGPR at 64 (R8 proved this workload fits) -> 8 blocks/CU
// resident (16KB LDS x 8 = 128KB < 160KB) = full 32-wave occupancy. Fused kernels interleave
// the A/B halves by block parity so heavy (NG=6) and light (NG=3) blocks co-schedule.
struct Seg { const h16* p[6]; int st[6]; int of[6]; };
#define RB32 ((NN + 31) / 32)

template <int G>
__device__ __forceinline__ void stage_g(as3h16* lds, const Seg& seg, int bi, int lane, int cq) {
    int r16 = lane & 15, kg = lane >> 4;
    int gr0 = bi * 32 + (cq & 1) * 16 + r16; if (gr0 >= NN) gr0 = NN - 1;
    gld_lds16(seg.p[G] + (size_t)gr0 * seg.st[G] + seg.of[G] + (cq >> 1) * 32 + kg * 8,
              lds + (G & 3) * 2048 + cq * 512);
}

template <int G, int NG, int CT>
__device__ __forceinline__ void gsteps(as3h16* lds, const Seg& seg, int bi, int lane, int cq,
                                       half8 (&wreg)[NG * 2][CT], f32x4 (&acc)[2][CT]) {
    if constexpr (G < NG) {
        constexpr int OUT = (NG - 1 - G) >= 2 ? 2 : (NG - 1 - G);
        wait_lgkm0_vm<OUT>();            // own stage of group G retired; newer stages stay in flight
        __builtin_amdgcn_s_barrier();    // all waves' chunks of G visible; slot (G-1)&3 free
        asm volatile("" ::: "memory");
        if constexpr (G + 3 < NG) stage_g<G + 3>(lds, seg, bi, lane, cq);
        #pragma unroll
        for (int kk = 0; kk < 2; ++kk) {
            half8 af[2];
            #pragma unroll
            for (int s = 0; s < 2; ++s)
                af[s] = *(const as3half8*)(lds + (G & 3) * 2048 + (kk * 2 + s) * 512 + lane * 8);
            #pragma unroll
            for (int c = 0; c < CT; ++c)
                #pragma unroll
                for (int s = 0; s < 2; ++s)
                    acc[s][c] = __builtin_amdgcn_mfma_f32_16x16x32_f16(af[s], wreg[2 * G + kk][c], acc[s][c], 0, 0, 0);
        }
        gsteps<G + 1, NG, CT>(lds, seg, bi, lane, cq, wreg, acc);
    }
}

template <int NG, int NO, int CT, int EPI, int XEPI>
__device__ __forceinline__ void mmg_body(int bi, const Seg& seg, const h16* __restrict__ Wf,
    const float* __restrict__ Wx, const float* __restrict__ x, const float* __restrict__ txx, int t,
    const float* __restrict__ Ba, const float* __restrict__ Bb,
    const h16* Hprev, h16* zbuf, h16* rhh, h16* houth, as3h16* lds) {
    constexpr int KS = NG * 2;
    constexpr int NT = NO / 16;
    int tid = threadIdx.x, lane = tid & 63, cq = tid >> 6; // 4 waves; cq = col quarter & stage chunk
    int ctb = cq * CT;
    int r16 = lane & 15;
    int rg4 = (lane >> 4) * 4;

    half8 wreg[KS][CT];
    #pragma unroll
    for (int ks = 0; ks < KS; ++ks)
        #pragma unroll
        for (int c = 0; c < CT; ++c)
            wreg[ks][c] = *(const half8*)(Wf + (((size_t)ks * NT + ctb + c) * 64 + lane) * 8);

    stage_g<0>(lds, seg, bi, lane, cq);
    stage_g<1>(lds, seg, bi, lane, cq);
    stage_g<2>(lds, seg, bi, lane, cq);

    f32x4 acc[2][CT];
    #pragma unroll
    for (int s = 0; s < 2; ++s)
        #pragma unroll
        for (int c = 0; c < CT; ++c) acc[s][c] = (f32x4){0.f, 0.f, 0.f, 0.f};

    gsteps<0, NG, CT>(lds, seg, bi, lane, cq, wreg, acc);

    int row0 = bi * 32;
    #pragma unroll
    for (int s = 0; s < 2; ++s) {
        int rbase = row0 + s * 16 + rg4;
        float xa0[4], xa1[4]; float4 tg[4];
        if (XEPI) {
            #pragma unroll
            for (int r = 0; r < 4; ++r) {
                int row = rbase + r; if (row >= NN) row = NN - 1;
                xa0[r] = x[(size_t)row * 24 + t];
                xa1[r] = x[(size_t)row * 24 + 12 + t];
                tg[r] = *(const float4*)&txx[((size_t)t * NN + row) * 4];
            }
        }
        #pragma unroll
        for (int c = 0; c < CT; ++c) {
            int col = (ctb + c) * 16 + r16;
            float w0, w1, w2, w3, w4, w5;
            if (XEPI) {
                w0 = Wx[col]; w1 = Wx[NO + col]; w2 = Wx[2 * NO + col];
                w3 = Wx[3 * NO + col]; w4 = Wx[4 * NO + col]; w5 = Wx[5 * NO + col];
            }
            float bb = (EPI == 0) ? (col < 64 ? Ba[col] : Bb[col - 64]) : Ba[col];
            #pragma unroll
            for (int r = 0; r < 4; ++r) {
                int row = rbase + r;
                if (row >= NN) continue;
                float v = acc[s][c][r] + bb;
                if (XEPI) v += xa0[r] * w0 + xa1[r] * w1 + tg[r].x * w2 + tg[r].y * w3 + tg[r].z * w4 + tg[r].w * w5;
                if (EPI == 0) {
                    if (col < 64) zbuf[(size_t)row * 64 + col] = (h16)sigm_(v);
                    else {
                        float rr_ = sigm_(v);
                        float hp = (float)Hprev[(size_t)row * 128 + col - 64];
                        rhh[(size_t)row * 128 + col - 64] = (h16)(rr_ * hp);
                    }
                } else {
                    float ht = tanh_(v);
                    float z = (float)zbuf[(size_t)row * 64 + col];
                    float hp = (float)Hprev[(size_t)row * 128 + col];
                    float hn = fmaxf(z * hp + (1.f - z) * ht, 0.f);
                    houth[(size_t)row * 128 + col] = (h16)hn;
                }
            }
        }
    }
}

template <int NG, int NO, int CT, int EPI, int XEPI>
__global__ __launch_bounds__(256, 8) void k_mmg(Seg seg, const h16* __restrict__ Wf,
    const float* __restrict__ Wx, const float* __restrict__ x, const float* __restrict__ txx, int t,
    const float* __restrict__ Ba, const float* __restrict__ Bb,
    const h16* Hprev, h16* zbuf, h16* rhh, h16* houth) {
    __shared__ __align__(16) h16 smem[4 * 2048];
    mmg_body<NG, NO, CT, EPI, XEPI>(blockIdx.x, seg, Wf, Wx, x, txx, t, Ba, Bb, Hprev, zbuf, rhh, houth,
                                    (as3h16*)smem);
}

// fused ZR pair, parity-interleaved: even blocks = L2ZR(t), odd blocks = L1ZR(t+1)
__global__ __launch_bounds__(256, 8) void k_mmzr2(Seg sA, Seg sB,
    const h16* __restrict__ wfA, const h16* __restrict__ wfB, const float* __restrict__ wxB,
    const float* __restrict__ x, const float* __restrict__ txx, int tB,
    const float* __restrict__ bAz, const float* __restrict__ bAr,
    const float* __restrict__ bBz, const float* __restrict__ bBr,
    const h16* hpA, h16* zA, h16* rhA,
    const h16* hpB, h16* zB, h16* rhB) {
    __shared__ __align__(16) h16 smem[4 * 2048];
    int bi = blockIdx.x >> 1;
    if ((blockIdx.x & 1) == 0)
        mmg_body<6, 128, 2, 0, 0>(bi, sA, wfA, nullptr, nullptr, nullptr, 0, bAz, bAr,
                                  hpA, zA, rhA, nullptr, (as3h16*)smem);
    else
        mmg_body<3, 128, 2, 0, 1>(bi, sB, wfB, wxB, x, txx, tB, bBz, bBr,
                                  hpB, zB, rhB, nullptr, (as3h16*)smem);
}

// fused H pair, parity-interleaved: even blocks = L2H(t), odd blocks = L1H(t+1)
__global__ __launch_bounds__(256, 8) void k_mmh2(Seg sA, Seg sB,
    const h16* __restrict__ wfA, const h16* __restrict__ wfB, const float* __restrict__ wxB,
    const float* __restrict__ x, const float* __restrict__ txx, int tB,
    const float* __restrict__ bAh, const float* __restrict__ bBh,
    h16* zA, const h16* hpA, h16* hoA,
    h16* zB, const h16* hpB, h16* hoB) {
    __shared__ __align__(16) h16 smem[4 * 2048];
    int bi = blockIdx.x >> 1;
    if ((blockIdx.x & 1) == 0)
        mmg_body<6, 64, 1, 1, 0>(bi, sA, wfA, nullptr, nullptr, nullptr, 0, bAh, nullptr,
                                 hpA, zA, nullptr, hoA, (as3h16*)smem);
    else
        mmg_body<3, 64, 1, 1, 1>(bi, sB, wfB, wxB, x, txx, tB, bBh, nullptr,
                                 hpB, zB, nullptr, hoB, (as3h16*)smem);
}

// ---------------- final projection (pair-strided h2 input) ----------------
__global__ __launch_bounds__(256) void k_final(const h16* __restrict__ h2p, const float* __restrict__ lw,
                                               const float* __restrict__ lb, float* __restrict__ out) {
    __shared__ float sh[16 * 65];
    int t = threadIdx.x;
    int n0 = blockIdx.x * 16;
    int idx = t * 4;
    int nl = idx >> 6, h = idx & 63;
    h16x4 v = *(const h16x4*)&h2p[(size_t)(n0 + nl) * 128 + h];
    sh[nl * 65 + h] = (float)v[0]; sh[nl * 65 + h + 1] = (float)v[1];
    sh[nl * 65 + h + 2] = (float)v[2]; sh[nl * 65 + h + 3] = (float)v[3];
    __syncthreads();
    if (t < 192) {
        int n = t / 12, o = t % 12;
        float acc = lb[o];
        #pragma unroll 8
        for (int k = 0; k < 64; ++k) acc += sh[n * 65 + k] * lw[k * 12 + o];
        out[(size_t)(n0 + n) * 12 + o] = acc;
    }
}

// ---------------- orchestration (layer-pipelined, interleaved pair state) ----------------
extern "C" void kernel_launch(void* const* d_in, const int* in_sizes, int n_in,
                              void* d_out, int out_size, void* d_ws, size_t ws_size,
                              hipStream_t stream) {
    const float* x   = (const float*)d_in[0];
    const int*   ei  = (const int*)d_in[1];
    const float* ew  = (const float*)d_in[2];
    const float* w1z = (const float*)d_in[3];  const float* b1z = (const float*)d_in[4];
    const float* w1r = (const float*)d_in[5];  const float* b1r = (const float*)d_in[6];
    const float* w1h = (const float*)d_in[7];  const float* b1h = (const float*)d_in[8];
    const float* w2z = (const float*)d_in[9];  const float* b2z = (const float*)d_in[10];
    const float* w2r = (const float*)d_in[11]; const float* b2r = (const float*)d_in[12];
    const float* w2h = (const float*)d_in[13]; const float* b2h = (const float*)d_in[14];
    const float* lw  = (const float*)d_in[15]; const float* lb  = (const float*)d_in[16];
    float* out = (float*)d_out;
    float* ws  = (float*)d_ws;
    if (ws_size < WS_FLOATS * sizeof(float)) return;

    const int EHB = (EHALF + 255) / 256;
    k_zero<<<1024, 256, 0, stream>>>(ws);
    k_hist<<<EHB, 256, 0, stream>>>(ei, ws, 0);
    k_hist<<<EHB, 256, 0, stream>>>(ei, ws, EHALF);
    k_scanA<<<NBLK, 256, 0, stream>>>(ws);
    k_scanB<<<1, 256, 0, stream>>>(ws);
    k_scanC<<<NBLK, 256, 0, stream>>>(ws);
    k_scatter<<<EHB, 256, 0, stream>>>(ei, ew, ws, 0);
    k_scatter<<<EHB, 256, 0, stream>>>(ei, ew, ws, EHALF);
    k_norm<<<NN / 4, 256, 0, stream>>>(ws);
    k_aggx<<<NN / 8, 256, 0, stream>>>(x, ws);
    k_packall<<<437, 256, 0, stream>>>(w1z, w1r, w1h, w2z, w2r, w2h, ws);

    h16* pEven = (h16*)(ws + O_PX0); // pairX_t, t even: [h1(t) | h2(t-1)]
    h16* pOdd  = (h16*)(ws + O_PX1); // pairX_t, t odd
    h16* pzr   = (h16*)(ws + O_PZR); // [rhh1 | rhh2]
    h16* z1    = (h16*)(ws + O_Z1);
    h16* z2    = (h16*)(ws + O_Z2);
    h16* txA = (h16*)(ws + O_TXA);
    h16* txB = (h16*)(ws + O_TXB);
    const float* txx = ws + O_TXX;
    const h16* wf1zr = (const h16*)(ws + O_WF1ZR);
    const h16* wf1h  = (const h16*)(ws + O_WF1H);
    const h16* wf2zr = (const h16*)(ws + O_WF2ZR);
    const h16* wf2h  = (const h16*)(ws + O_WF2H);
    const float* wx1zr = ws + O_WX1ZR;
    const float* wx1h  = ws + O_WX1H;
    const int GAP = NN / 16;        // 3125 dual-gather blocks
    const int GA1 = (NN + 31) / 32; // 1563 single-gather blocks

    auto s1zr = [&](h16* px) -> Seg {
        return {{px, txB, txB, nullptr, nullptr, nullptr}, {128, 256, 256, 0, 0, 0}, {0, 0, 128, 0, 0, 0}};
    };
    Seg s1h = {{pzr, txA, txA, nullptr, nullptr, nullptr}, {128, 128, 128, 0, 0, 0}, {0, 0, 64, 0, 0, 0}};
    auto s2zr = [&](h16* px) -> Seg {
        return {{px, px, txB, txB, txB, txB}, {128, 128, 256, 256, 256, 256}, {0, 64, 0, 64, 128, 192}};
    };
    auto s2h = [&](h16* px) -> Seg {
        return {{px, pzr, txB, txB, txB, txB}, {128, 128, 256, 256, 256, 256}, {0, 64, 0, 64, 128, 192}};
    };

    // ---- prologue (t=0, closed-form: all t=0 L1 A-operands are zero) ----
    k_l1zr0<<<NN / 4, 256, 0, stream>>>(x, txx, wx1zr, b1z, ws);
    k_l1h0<<<NN / 4, 256, 0, stream>>>(x, txx, wx1h, b1h, ws);
    k_aggP<<<GAP, 256, 0, stream>>>(pEven, txB, 256, 0, 128, txB, 256, 64, 192, ws);

    // ---- steady: L2 at t, L1 at t+1 (t = 0..10) ----
    for (int t = 0; t < TT - 1; ++t) {
        h16* pxT  = (t & 1) ? pOdd : pEven;  // pairX_t
        h16* pxT1 = (t & 1) ? pEven : pOdd;  // pairX_{t+1}
        k_mmzr2<<<RB32 * 2, 256, 0, stream>>>(s2zr(pxT), s1zr(pxT), wf2zr, wf1zr, wx1zr,
            x, txx, t + 1, b2z, b2r, b1z, b1r,
            pxT + 64, z2, pzr + 64,
            pxT,      z1, pzr);
        k_aggP<<<GAP, 256, 0, stream>>>(pzr, txA, 128, 0, 64, txB, 256, 64, 192, ws);
        k_mmh2<<<RB32 * 2, 256, 0, stream>>>(s2h(pxT), s1h, wf2h, wf1h, wx1h,
            x, txx, t + 1, b2h, b1h,
            z2, pxT + 64, pxT1 + 64,
            z1, pxT,      pxT1);
        k_aggP<<<GAP, 256, 0, stream>>>(pxT1, txB, 256, 0, 128, txB, 256, 64, 192, ws);
    }

    // ---- epilogue: L2 at t = 11 (pairX_11 = pOdd) ----
    k_mmg<6, 128, 2, 0, 0><<<RB32, 256, 0, stream>>>(s2zr(pOdd), wf2zr, nullptr, nullptr, nullptr, 0,
        b2z, b2r, pOdd + 64, z2, pzr + 64, nullptr);
    k_agg1<<<GA1, 256, 0, stream>>>(pzr + 64, 128, txB, 256, 64, 192, ws);
    k_mmg<6, 64, 1, 1, 0><<<RB32, 256, 0, stream>>>(s2h(pOdd), wf2h, nullptr, nullptr, nullptr, 0,
        b2h, nullptr, pOdd + 64, z2, nullptr, pEven + 64);
    k_final<<<NN / 16, 256, 0, stream>>>(pEven + 64, lw, lb, out);
}

// Round 13
// 1602.704 us; speedup vs baseline: 1.3467x; 1.3467x over previous
//
#include <hip/hip_runtime.h>

#define NN 50000
#define NE 800000
#define TT 12
#define NBIN (4 * NN)
#define NBLK ((NBIN + 255) / 256)
#define EHALF (NE / 2)

typedef _Float16 h16;
typedef __attribute__((ext_vector_type(2))) _Float16 h16x2;
typedef __attribute__((ext_vector_type(4))) _Float16 h16x4;
typedef __attribute__((ext_vector_type(8))) _Float16 half8;
typedef __attribute__((ext_vector_type(4))) float f32x4;
typedef __attribute__((address_space(3))) h16 as3h16;
typedef __attribute__((address_space(3))) half8 as3half8;

static constexpr size_t alignup(size_t x) { return (x + 255) & ~(size_t)255; }
// workspace layout (float units)
static constexpr size_t O_CNT  = 0;                                   // (NBIN+1) ints
static constexpr size_t O_CUR  = alignup(O_CNT + NBIN + 1);           // NBIN ints (dead; layout kept)
static constexpr size_t O_DEGO = alignup(O_CUR + NBIN);               // NN f
static constexpr size_t O_BSUM = alignup(O_DEGO + NN);                // 1024 ints
static constexpr size_t O_BEXC = O_BSUM + 1024;                       // 1024 ints
static constexpr size_t O_EDG  = alignup(O_BEXC + 1024);              // NE uint2 {src, no|ni h16x2}
static constexpr size_t O_TXX  = alignup(O_EDG + (size_t)NE * 2);     // [T][NN][4] f32 (first NE ints reused as rank[] between k_hist and k_scatter)
static constexpr size_t O_WF1ZR= alignup(O_TXX + (size_t)TT * NN * 4);// 12288 f
static constexpr size_t O_WF1H = alignup(O_WF1ZR + 12288);            // 6144 f
static constexpr size_t O_WF2ZR= alignup(O_WF1H + 6144);              // 24576 f
static constexpr size_t O_WF2H = alignup(O_WF2ZR + 24576);            // 12288 f
static constexpr size_t O_WX1ZR= alignup(O_WF2H + 12288);             // 768 f
static constexpr size_t O_WX1H = alignup(O_WX1ZR + 768);              // 384 f
// interleaved pair state buffers: rows of 128 h16 = [partA(64) | partB(64)]
static constexpr size_t O_PX0  = alignup(O_WX1H + 384);               // pairX even: [h1(t) | h2(t-1)], t even
static constexpr size_t O_PX1  = O_PX0 + (size_t)NN * 64;             // pairX odd
static constexpr size_t O_PZR  = O_PX1 + (size_t)NN * 64;             // [rhh1 | rhh2]
static constexpr size_t O_Z1   = O_PZR + (size_t)NN * 64;             // z1 h16 (stride 64)
static constexpr size_t O_Z2   = O_Z1 + (size_t)NN * 32;              // z2 h16
static constexpr size_t O_TXA  = alignup(O_Z2 + (size_t)NN * 32);     // NN*128 h16
static constexpr size_t O_TXB  = alignup(O_TXA + (size_t)NN * 64);    // NN*256 h16
static constexpr size_t WS_FLOATS = O_TXB + (size_t)NN * 128;

__device__ __forceinline__ float sigm_(float x) { return 1.f / (1.f + __expf(-x)); }
__device__ __forceinline__ float tanh_(float x) { float e = __expf(2.f * x); return 1.f - 2.f / (e + 1.f); }

__device__ __forceinline__ void gld_lds16(const h16* g, as3h16* l) {
    __builtin_amdgcn_global_load_lds(
        (const __attribute__((address_space(1))) void*)g,
        (__attribute__((address_space(3))) void*)l, 16, 0, 0);
}

template <int N>
__device__ __forceinline__ void wait_lgkm0_vm() {
    if constexpr (N == 0)      asm volatile("s_waitcnt lgkmcnt(0) vmcnt(0)" ::: "memory");
    else if constexpr (N == 1) asm volatile("s_waitcnt lgkmcnt(0) vmcnt(1)" ::: "memory");
    else                       asm volatile("s_waitcnt lgkmcnt(0) vmcnt(2)" ::: "memory");
}

// ---------------- preprocessing ----------------

// zero: counters + pEven only (txB/pOdd/txA zeroing is dead: t=0 L1 is closed-form and the
// prologue aggP fully writes txB before first read).
__global__ __launch_bounds__(256) void k_zero(float* ws) {
    size_t i = (size_t)blockIdx.x * 256 + threadIdx.x;
    size_t stride = (size_t)gridDim.x * 256;
    for (size_t p = i; p < O_BSUM + 2048; p += stride) ((int*)ws)[p] = 0;
    for (size_t p = i; p < (size_t)NN * 64; p += stride) ws[O_PX0 + p] = 0.f; // pEven (h2(-1)=0; partA overwritten by k_l1h0)
}

// bin = dest*4 + src_quarter; single scattered atomic per edge, rank stored for atomic-free
// scatter. Half-range split keeps these below the steady-loop kernels in the top-5.
__global__ __launch_bounds__(256) void k_hist(const int* ei, float* ws, int ebase) {
    int e = ebase + blockIdx.x * 256 + threadIdx.x;
    if (e >= NE || e >= ebase + EHALF) return;
    int r = ei[e], c = ei[NE + e];
    int bin = c * 4 + r / 12500;
    int rk = atomicAdd((int*)ws + O_CNT + bin, 1);
    ((int*)ws)[O_TXX + e] = rk; // coalesced; O_TXX not live until k_aggx (which overwrites it fully)
}

__global__ __launch_bounds__(256) void k_scanA(float* ws) {
    __shared__ int sh[256];
    int t = threadIdx.x, i = blockIdx.x * 256 + t;
    int v = (i < NBIN) ? ((int*)ws)[O_CNT + i] : 0;
    sh[t] = v; __syncthreads();
    for (int o = 128; o > 0; o >>= 1) { if (t < o) sh[t] += sh[t + o]; __syncthreads(); }
    if (t == 0) ((int*)ws)[O_BSUM + blockIdx.x] = sh[0];
}

__global__ __launch_bounds__(256) void k_scanB(float* ws) {
    __shared__ int tot[256];
    int t = threadIdx.x;
    int* bsum = (int*)ws + O_BSUM;
    int* bexc = (int*)ws + O_BEXC;
    int base = t * 4;
    int v0 = (base + 0 < NBLK) ? bsum[base + 0] : 0;
    int v1 = (base + 1 < NBLK) ? bsum[base + 1] : 0;
    int v2 = (base + 2 < NBLK) ? bsum[base + 2] : 0;
    int v3 = (base + 3 < NBLK) ? bsum[base + 3] : 0;
    int sum = v0 + v1 + v2 + v3;
    tot[t] = sum; __syncthreads();
    for (int o = 1; o < 256; o <<= 1) {
        int a = (t >= o) ? tot[t - o] : 0;
        __syncthreads(); tot[t] += a; __syncthreads();
    }
    int excl = tot[t] - sum;
    if (base + 0 < NBLK) bexc[base + 0] = excl;
    if (base + 1 < NBLK) bexc[base + 1] = excl + v0;
    if (base + 2 < NBLK) bexc[base + 2] = excl + v0 + v1;
    if (base + 3 < NBLK) bexc[base + 3] = excl + v0 + v1 + v2;
    if (t == 255) ((int*)ws)[O_CNT + NBIN] = tot[255];
}

__global__ __launch_bounds__(256) void k_scanC(float* ws) {
    __shared__ int sh[256];
    int t = threadIdx.x, b = blockIdx.x, i = b * 256 + t;
    int v = (i < NBIN) ? ((int*)ws)[O_CNT + i] : 0;
    sh[t] = v; __syncthreads();
    for (int o = 1; o < 256; o <<= 1) {
        int a = (t >= o) ? sh[t - o] : 0;
        __syncthreads(); sh[t] += a; __syncthreads();
    }
    if (i < NBIN) ((int*)ws)[O_CNT + i] = ((int*)ws)[O_BEXC + b] + sh[t] - v;
}

// slot = offs[bin] + precomputed rank (no atomic); dego atomic lives here. Half-range split.
__global__ __launch_bounds__(256) void k_scatter(const int* ei, const float* ew, float* ws, int ebase) {
    int e = ebase + blockIdx.x * 256 + threadIdx.x;
    if (e >= NE || e >= ebase + EHALF) return;
    int r = ei[e], c = ei[NE + e];
    float w = ew[e];
    atomicAdd(ws + O_DEGO + r, w);
    int bin = c * 4 + r / 12500;
    int p = ((const int*)ws)[O_CNT + bin] + ((const int*)ws)[O_TXX + e];
    uint2 rec; rec.x = (unsigned)r; rec.y = __float_as_uint(w);
    ((uint2*)(ws + O_EDG))[p] = rec;
}

// per-node: deg_in = segment sum of w; rewrite records {src, (no,ni) h16x2}
__global__ __launch_bounds__(256) void k_norm(float* ws) {
    int n = blockIdx.x * 4 + (threadIdx.x >> 6);
    int lane = threadIdx.x & 63;
    const int* offs = (const int*)ws + O_CNT;
    uint2* recs = (uint2*)(ws + O_EDG);
    const float* dego = ws + O_DEGO;
    int e0 = offs[4 * n], e1 = offs[4 * n + 4];
    float s = 0.f;
    for (int e = e0 + lane; e < e1; e += 64) s += __uint_as_float(recs[e].y);
    #pragma unroll
    for (int m = 1; m < 64; m <<= 1) s += __shfl_xor(s, m);
    float inv = 1.f / s;
    for (int e = e0 + lane; e < e1; e += 64) {
        uint2 r = recs[e];
        float w = __uint_as_float(r.y);
        h16x2 nv; nv.x = (h16)(w / dego[r.x]); nv.y = (h16)(w * inv);
        r.y = __builtin_bit_cast(unsigned int, nv);
        recs[e] = r;
    }
}

// x aggregation for ALL timesteps, 2 nodes/wave: txx[t][n][c]
__global__ __launch_bounds__(256) void k_aggx(const float* __restrict__ x, float* __restrict__ ws) {
    int tid = threadIdx.x;
    int n = blockIdx.x * 8 + (tid >> 5);
    int l = tid & 31;
    const int* offs = (const int*)ws + O_CNT;
    const uint2* recs = (const uint2*)(ws + O_EDG);
    int e0 = offs[4 * n], e1 = offs[4 * n + 4];
    int f = l / 12, tt2 = l % 12;
    bool act = l < 24;
    float ao = 0.f, ai = 0.f;
    uint2 rc0, rc1;
    if (e0 < e1) {
        rc0 = recs[e0];
        rc1 = recs[(e0 + 1 < e1) ? e0 + 1 : e1 - 1];
    }
    for (int e = e0; e < e1; e += 2) {
        uint2 c0 = rc0, c1 = rc1;
        int n2 = (e + 2 < e1) ? e + 2 : e1 - 1, n3 = (e + 3 < e1) ? e + 3 : e1 - 1;
        rc0 = recs[n2]; rc1 = recs[n3];
        h16x2 nv0 = __builtin_bit_cast(h16x2, c0.y);
        h16x2 nv1 = __builtin_bit_cast(h16x2, c1.y);
        bool ok1 = (e + 1 < e1);
        float no1 = ok1 ? (float)nv1.x : 0.f, ni1 = ok1 ? (float)nv1.y : 0.f;
        if (act) {
            float v0 = x[(size_t)c0.x * 24 + f * 12 + tt2];
            float v1 = x[(size_t)c1.x * 24 + f * 12 + tt2];
            ao += (float)nv0.x * v0 + no1 * v1;
            ai += (float)nv0.y * v0 + ni1 * v1;
        }
    }
    if (act) {
        ws[O_TXX + ((size_t)tt2 * NN + n) * 4 + f] = ao;
        ws[O_TXX + ((size_t)tt2 * NN + n) * 4 + 2 + f] = ai;
    }
}

// ---------------- weight packing ----------------
__device__ void packf_dev(int L, int NO, const float* wa, const float* wb, h16* Wf, int idx) {
    int C = (L == 1) ? 66 : 128;
    int NT = NO / 16;
    int j = idx & 7, l = (idx >> 3) & 63;
    int rest = idx >> 9;
    int ct = rest % NT, ks = rest / NT;
    int k = ks * 32 + ((l >> 4) << 3) + j;
    int col = ct * 16 + (l & 15);
    const float* w = wa; int jj = col;
    if (NO == 128 && col >= 64) { w = wb; jj = col - 64; }
    int G = k >> 6, c6 = k & 63, sg, crow;
    if (L == 1) { sg = G; crow = 2 + c6; }
    else        { sg = G >> 1; crow = ((G & 1) << 6) + c6; }
    float v;
    if (sg == 0)      v = w[(size_t)(0 * C + crow) * 64 + jj] + w[(size_t)(2 * C + crow) * 64 + jj];
    else if (sg == 1) v = w[(size_t)(1 * C + crow) * 64 + jj];
    else              v = w[(size_t)(3 * C + crow) * 64 + jj];
    Wf[idx] = (h16)v;
}

__device__ void packx_dev(int NO, const float* wa, const float* wb, float* Wx, int idx) {
    if (idx >= 6 * NO) return;
    int cc = idx / NO, col = idx % NO;
    const float* w = wa; int jj = col;
    if (NO == 128 && col >= 64) { w = wb; jj = col - 64; }
    int sg = cc >> 1, c = cc & 1;
    float v;
    if (sg == 0)      v = w[(size_t)(0 * 66 + c) * 64 + jj] + w[(size_t)(2 * 66 + c) * 64 + jj];
    else if (sg == 1) v = w[(size_t)(1 * 66 + c) * 64 + jj];
    else              v = w[(size_t)(3 * 66 + c) * 64 + jj];
    Wx[idx] = v;
}

__global__ __launch_bounds__(256) void k_packall(const float* w1z, const float* w1r, const float* w1h,
    const float* w2z, const float* w2r, const float* w2h, float* ws) {
    int b = blockIdx.x, t = threadIdx.x;
    if (b < 96)       packf_dev(1, 128, w1z, w1r, (h16*)(ws + O_WF1ZR), b * 256 + t);
    else if (b < 144) packf_dev(1, 64,  w1h, nullptr, (h16*)(ws + O_WF1H), (b - 96) * 256 + t);
    else if (b < 336) packf_dev(2, 128, w2z, w2r, (h16*)(ws + O_WF2ZR), (b - 144) * 256 + t);
    else if (b < 432) packf_dev(2, 64,  w2h, nullptr, (h16*)(ws + O_WF2H), (b - 336) * 256 + t);
    else {
        int idx = (b - 432) * 256 + t;
        if (idx < 768) packx_dev(128, w1z, w1r, ws + O_WX1ZR, idx);
        int idx2 = idx - 768;
        if (idx2 >= 0 && idx2 < 384) packx_dev(64, w1h, nullptr, ws + O_WX1H, idx2);
    }
}

// ---------------- t=0 closed-form prologue (A-operands identically zero at t=0) ----------------
__global__ __launch_bounds__(256) void k_l1zr0(const float* __restrict__ x, const float* __restrict__ txx,
    const float* __restrict__ wx, const float* __restrict__ bz, float* ws) {
    int tid = threadIdx.x;
    int n = blockIdx.x * 4 + (tid >> 6), col = tid & 63;
    float xa0 = x[(size_t)n * 24], xa1 = x[(size_t)n * 24 + 12];
    float4 tg = *(const float4*)&txx[(size_t)n * 4];
    float v = bz[col] + xa0 * wx[col] + xa1 * wx[128 + col] + tg.x * wx[256 + col]
            + tg.y * wx[384 + col] + tg.z * wx[512 + col] + tg.w * wx[640 + col];
    ((h16*)(ws + O_Z1))[(size_t)n * 64 + col] = (h16)sigm_(v);
}

__global__ __launch_bounds__(256) void k_l1h0(const float* __restrict__ x, const float* __restrict__ txx,
    const float* __restrict__ wx, const float* __restrict__ bh, float* ws) {
    int tid = threadIdx.x;
    int n = blockIdx.x * 4 + (tid >> 6), col = tid & 63;
    float xa0 = x[(size_t)n * 24], xa1 = x[(size_t)n * 24 + 12];
    float4 tg = *(const float4*)&txx[(size_t)n * 4];
    float v = bh[col] + xa0 * wx[col] + xa1 * wx[64 + col] + tg.x * wx[128 + col]
            + tg.y * wx[192 + col] + tg.z * wx[256 + col] + tg.w * wx[320 + col];
    float z = (float)((const h16*)(ws + O_Z1))[(size_t)n * 64 + col];
    float hn = fmaxf((1.f - z) * tanh_(v), 0.f);
    ((h16*)(ws + O_PX0))[(size_t)n * 128 + col] = (h16)hn;
}

// ---- dual gather over interleaved pair table: 4 nodes/wave, 16 lanes x 16B = 256B row, 4-edge unroll ----
__global__ __launch_bounds__(256) void k_aggP(
    const h16* __restrict__ T,
    h16* __restrict__ outA, int orsA, int oA, int iA,
    h16* __restrict__ outB, int orsB, int oB, int iB,
    const float* __restrict__ ws) {
    int tid = threadIdx.x, lane = tid & 63, wv = tid >> 6;
    int q = lane >> 4, fl = lane & 15;
    int n = blockIdx.x * 16 + wv * 4 + q;
    const int* offs = (const int*)ws + O_CNT;
    const uint2* recs = (const uint2*)(ws + O_EDG);
    int e0 = offs[4 * n], e1 = offs[4 * n + 4];
    float ao[8] = {}, ai[8] = {};
    for (int e = e0; e < e1; e += 4) {
        int i1 = e + 1 < e1 ? e + 1 : e1 - 1;
        int i2 = e + 2 < e1 ? e + 2 : e1 - 1;
        int i3 = e + 3 < e1 ? e + 3 : e1 - 1;
        uint2 r0 = recs[e], r1 = recs[i1], r2 = recs[i2], r3 = recs[i3];
        half8 v0 = *(const half8*)(T + (size_t)r0.x * 128 + fl * 8);
        half8 v1 = *(const half8*)(T + (size_t)r1.x * 128 + fl * 8);
        half8 v2 = *(const half8*)(T + (size_t)r2.x * 128 + fl * 8);
        half8 v3 = *(const half8*)(T + (size_t)r3.x * 128 + fl * 8);
        h16x2 m0 = __builtin_bit_cast(h16x2, r0.y);
        h16x2 m1 = __builtin_bit_cast(h16x2, r1.y);
        h16x2 m2 = __builtin_bit_cast(h16x2, r2.y);
        h16x2 m3 = __builtin_bit_cast(h16x2, r3.y);
        float no0 = (float)m0.x, ni0 = (float)m0.y;
        float no1 = (e + 1 < e1) ? (float)m1.x : 0.f, ni1 = (e + 1 < e1) ? (float)m1.y : 0.f;
        float no2 = (e + 2 < e1) ? (float)m2.x : 0.f, ni2 = (e + 2 < e1) ? (float)m2.y : 0.f;
        float no3 = (e + 3 < e1) ? (float)m3.x : 0.f, ni3 = (e + 3 < e1) ? (float)m3.y : 0.f;
        #pragma unroll
        for (int j = 0; j < 8; ++j) {
            float f0 = (float)v0[j], f1 = (float)v1[j], f2 = (float)v2[j], f3 = (float)v3[j];
            ao[j] += no0 * f0 + no1 * f1 + no2 * f2 + no3 * f3;
            ai[j] += ni0 * f0 + ni1 * f1 + ni2 * f2 + ni3 * f3;
        }
    }
    h16* outP = (fl < 8) ? outA : outB;
    int ors = (fl < 8) ? orsA : orsB;
    int fo = (fl < 8) ? fl : fl - 8;
    int oT = ((fl < 8) ? oA : oB) + fo * 8;
    int iT = ((fl < 8) ? iA : iB) + fo * 8;
    half8 wo, wi;
    #pragma unroll
    for (int j = 0; j < 8; ++j) { wo[j] = (h16)ao[j]; wi[j] = (h16)ai[j]; }
    *(half8*)(outP + (size_t)n * ors + oT) = wo;
    *(half8*)(outP + (size_t)n * ors + iT) = wi;
}

// ---- single-table gather (stride hs rows): 8 nodes/wave, 8 lanes x 16B ----
__global__ __launch_bounds__(256) void k_agg1(
    const h16* __restrict__ T, int hs,
    h16* __restrict__ out, int ors, int oA, int iA,
    const float* __restrict__ ws) {
    int tid = threadIdx.x, lane = tid & 63, wv = tid >> 6;
    int q = lane >> 3, fl = lane & 7;
    int n = blockIdx.x * 32 + wv * 8 + q;
    if (n >= NN) n = NN - 1;
    const int* offs = (const int*)ws + O_CNT;
    const uint2* recs = (const uint2*)(ws + O_EDG);
    int e0 = offs[4 * n], e1 = offs[4 * n + 4];
    float ao[8] = {}, ai[8] = {};
    for (int e = e0; e < e1; e += 2) {
        int i1 = e + 1 < e1 ? e + 1 : e1 - 1;
        uint2 r0 = recs[e], r1 = recs[i1];
        half8 v0 = *(const half8*)(T + (size_t)r0.x * hs + fl * 8);
        half8 v1 = *(const half8*)(T + (size_t)r1.x * hs + fl * 8);
        h16x2 m0 = __builtin_bit_cast(h16x2, r0.y);
        h16x2 m1 = __builtin_bit_cast(h16x2, r1.y);
        float no0 = (float)m0.x, ni0 = (float)m0.y;
        float no1 = (e + 1 < e1) ? (float)m1.x : 0.f, ni1 = (e + 1 < e1) ? (float)m1.y : 0.f;
        #pragma unroll
        for (int j = 0; j < 8; ++j) {
            float f0 = (float)v0[j], f1 = (float)v1[j];
            ao[j] += no0 * f0 + no1 * f1;
            ai[j] += ni0 * f0 + ni1 * f1;
        }
    }
    half8 wo, wi;
    #pragma unroll
    for (int j = 0; j < 8; ++j) { wo[j] = (h16)ao[j]; wi[j] = (h16)ai[j]; }
    *(half8*)(out + (size_t)n * ors + oA + fl * 8) = wo;
    *(half8*)(out + (size_t)n * ors + iA + fl * 8) = wi;
}

// ---------------- MFMA dconv GEMM: 4-wave (256t) blocks, 32-row tiles, 4-slot pipelined LDS A ----------------
// __launch_bounds__(256, 4): <=128 VGPR, no spill (R12's (256,8) forced a 32-VGPR cap ->
// scratch catastrophe). 4 blocks/CU x 16KB LDS; R11-proven regime. Fused kernels interleave
// the A/B halves by block parity so heavy (NG=6) and light (NG=3) blocks co-schedule.
struct Seg { const h16* p[6]; int st[6]; int of[6]; };
#define RB32 ((NN + 31) / 32)

template <int G>
__device__ __forceinline__ void stage_g(as3h16* lds, const Seg& seg, int bi, int lane, int cq) {
    int r16 = lane & 15, kg = lane >> 4;
    int gr0 = bi * 32 + (cq & 1) * 16 + r16; if (gr0 >= NN) gr0 = NN - 1;
    gld_lds16(seg.p[G] + (size_t)gr0 * seg.st[G] + seg.of[G] + (cq >> 1) * 32 + kg * 8,
              lds + (G & 3) * 2048 + cq * 512);
}

template <int G, int NG, int CT>
__device__ __forceinline__ void gsteps(as3h16* lds, const Seg& seg, int bi, int lane, int cq,
                                       half8 (&wreg)[NG * 2][CT], f32x4 (&acc)[2][CT]) {
    if constexpr (G < NG) {
        constexpr int OUT = (NG - 1 - G) >= 2 ? 2 : (NG - 1 - G);
        wait_lgkm0_vm<OUT>();            // own stage of group G retired; newer stages stay in flight
        __builtin_amdgcn_s_barrier();    // all waves' chunks of G visible; slot (G-1)&3 free
        asm volatile("" ::: "memory");
        if constexpr (G + 3 < NG) stage_g<G + 3>(lds, seg, bi, lane, cq);
        #pragma unroll
        for (int kk = 0; kk < 2; ++kk) {
            half8 af[2];
            #pragma unroll
            for (int s = 0; s < 2; ++s)
                af[s] = *(const as3half8*)(lds + (G & 3) * 2048 + (kk * 2 + s) * 512 + lane * 8);
            #pragma unroll
            for (int c = 0; c < CT; ++c)
                #pragma unroll
                for (int s = 0; s < 2; ++s)
                    acc[s][c] = __builtin_amdgcn_mfma_f32_16x16x32_f16(af[s], wreg[2 * G + kk][c], acc[s][c], 0, 0, 0);
        }
        gsteps<G + 1, NG, CT>(lds, seg, bi, lane, cq, wreg, acc);
    }
}

template <int NG, int NO, int CT, int EPI, int XEPI>
__device__ __forceinline__ void mmg_body(int bi, const Seg& seg, const h16* __restrict__ Wf,
    const float* __restrict__ Wx, const float* __restrict__ x, const float* __restrict__ txx, int t,
    const float* __restrict__ Ba, const float* __restrict__ Bb,
    const h16* Hprev, h16* zbuf, h16* rhh, h16* houth, as3h16* lds) {
    constexpr int KS = NG * 2;
    constexpr int NT = NO / 16;
    int tid = threadIdx.x, lane = tid & 63, cq = tid >> 6; // 4 waves; cq = col quarter & stage chunk
    int ctb = cq * CT;
    int r16 = lane & 15;
    int rg4 = (lane >> 4) * 4;

    half8 wreg[KS][CT];
    #pragma unroll
    for (int ks = 0; ks < KS; ++ks)
        #pragma unroll
        for (int c = 0; c < CT; ++c)
            wreg[ks][c] = *(const half8*)(Wf + (((size_t)ks * NT + ctb + c) * 64 + lane) * 8);

    stage_g<0>(lds, seg, bi, lane, cq);
    stage_g<1>(lds, seg, bi, lane, cq);
    stage_g<2>(lds, seg, bi, lane, cq);

    f32x4 acc[2][CT];
    #pragma unroll
    for (int s = 0; s < 2; ++s)
        #pragma unroll
        for (int c = 0; c < CT; ++c) acc[s][c] = (f32x4){0.f, 0.f, 0.f, 0.f};

    gsteps<0, NG, CT>(lds, seg, bi, lane, cq, wreg, acc);

    int row0 = bi * 32;
    #pragma unroll
    for (int s = 0; s < 2; ++s) {
        int rbase = row0 + s * 16 + rg4;
        float xa0[4], xa1[4]; float4 tg[4];
        if (XEPI) {
            #pragma unroll
            for (int r = 0; r < 4; ++r) {
                int row = rbase + r; if (row >= NN) row = NN - 1;
                xa0[r] = x[(size_t)row * 24 + t];
                xa1[r] = x[(size_t)row * 24 + 12 + t];
                tg[r] = *(const float4*)&txx[((size_t)t * NN + row) * 4];
            }
        }
        #pragma unroll
        for (int c = 0; c < CT; ++c) {
            int col = (ctb + c) * 16 + r16;
            float w0, w1, w2, w3, w4, w5;
            if (XEPI) {
                w0 = Wx[col]; w1 = Wx[NO + col]; w2 = Wx[2 * NO + col];
                w3 = Wx[3 * NO + col]; w4 = Wx[4 * NO + col]; w5 = Wx[5 * NO + col];
            }
            float bb = (EPI == 0) ? (col < 64 ? Ba[col] : Bb[col - 64]) : Ba[col];
            #pragma unroll
            for (int r = 0; r < 4; ++r) {
                int row = rbase + r;
                if (row >= NN) continue;
                float v = acc[s][c][r] + bb;
                if (XEPI) v += xa0[r] * w0 + xa1[r] * w1 + tg[r].x * w2 + tg[r].y * w3 + tg[r].z * w4 + tg[r].w * w5;
                if (EPI == 0) {
                    if (col < 64) zbuf[(size_t)row * 64 + col] = (h16)sigm_(v);
                    else {
                        float rr_ = sigm_(v);
                        float hp = (float)Hprev[(size_t)row * 128 + col - 64];
                        rhh[(size_t)row * 128 + col - 64] = (h16)(rr_ * hp);
                    }
                } else {
                    float ht = tanh_(v);
                    float z = (float)zbuf[(size_t)row * 64 + col];
                    float hp = (float)Hprev[(size_t)row * 128 + col];
                    float hn = fmaxf(z * hp + (1.f - z) * ht, 0.f);
                    houth[(size_t)row * 128 + col] = (h16)hn;
                }
            }
        }
    }
}

template <int NG, int NO, int CT, int EPI, int XEPI>
__global__ __launch_bounds__(256, 4) void k_mmg(Seg seg, const h16* __restrict__ Wf,
    const float* __restrict__ Wx, const float* __restrict__ x, const float* __restrict__ txx, int t,
    const float* __restrict__ Ba, const float* __restrict__ Bb,
    const h16* Hprev, h16* zbuf, h16* rhh, h16* houth) {
    __shared__ __align__(16) h16 smem[4 * 2048];
    mmg_body<NG, NO, CT, EPI, XEPI>(blockIdx.x, seg, Wf, Wx, x, txx, t, Ba, Bb, Hprev, zbuf, rhh, houth,
                                    (as3h16*)smem);
}

// fused ZR pair, parity-interleaved: even blocks = L2ZR(t), odd blocks = L1ZR(t+1)
__global__ __launch_bounds__(256, 4) void k_mmzr2(Seg sA, Seg sB,
    const h16* __restrict__ wfA, const h16* __restrict__ wfB, const float* __restrict__ wxB,
    const float* __restrict__ x, const float* __restrict__ txx, int tB,
    const float* __restrict__ bAz, const float* __restrict__ bAr,
    const float* __restrict__ bBz, const float* __restrict__ bBr,
    const h16* hpA, h16* zA, h16* rhA,
    const h16* hpB, h16* zB, h16* rhB) {
    __shared__ __align__(16) h16 smem[4 * 2048];
    int bi = blockIdx.x >> 1;
    if ((blockIdx.x & 1) == 0)
        mmg_body<6, 128, 2, 0, 0>(bi, sA, wfA, nullptr, nullptr, nullptr, 0, bAz, bAr,
                                  hpA, zA, rhA, nullptr, (as3h16*)smem);
    else
        mmg_body<3, 128, 2, 0, 1>(bi, sB, wfB, wxB, x, txx, tB, bBz, bBr,
                                  hpB, zB, rhB, nullptr, (as3h16*)smem);
}

// fused H pair, parity-interleaved: even blocks = L2H(t), odd blocks = L1H(t+1)
__global__ __launch_bounds__(256, 4) void k_mmh2(Seg sA, Seg sB,
    const h16* __restrict__ wfA, const h16* __restrict__ wfB, const float* __restrict__ wxB,
    const float* __restrict__ x, const float* __restrict__ txx, int tB,
    const float* __restrict__ bAh, const float* __restrict__ bBh,
    h16* zA, const h16* hpA, h16* hoA,
    h16* zB, const h16* hpB, h16* hoB) {
    __shared__ __align__(16) h16 smem[4 * 2048];
    int bi = blockIdx.x >> 1;
    if ((blockIdx.x & 1) == 0)
        mmg_body<6, 64, 1, 1, 0>(bi, sA, wfA, nullptr, nullptr, nullptr, 0, bAh, nullptr,
                                 hpA, zA, nullptr, hoA, (as3h16*)smem);
    else
        mmg_body<3, 64, 1, 1, 1>(bi, sB, wfB, wxB, x, txx, tB, bBh, nullptr,
                                 hpB, zB, nullptr, hoB, (as3h16*)smem);
}

// ---------------- final projection (pair-strided h2 input) ----------------
__global__ __launch_bounds__(256) void k_final(const h16* __restrict__ h2p, const float* __restrict__ lw,
                                               const float* __restrict__ lb, float* __restrict__ out) {
    __shared__ float sh[16 * 65];
    int t = threadIdx.x;
    int n0 = blockIdx.x * 16;
    int idx = t * 4;
    int nl = idx >> 6, h = idx & 63;
    h16x4 v = *(const h16x4*)&h2p[(size_t)(n0 + nl) * 128 + h];
    sh[nl * 65 + h] = (float)v[0]; sh[nl * 65 + h + 1] = (float)v[1];
    sh[nl * 65 + h + 2] = (float)v[2]; sh[nl * 65 + h + 3] = (float)v[3];
    __syncthreads();
    if (t < 192) {
        int n = t / 12, o = t % 12;
        float acc = lb[o];
        #pragma unroll 8
        for (int k = 0; k < 64; ++k) acc += sh[n * 65 + k] * lw[k * 12 + o];
        out[(size_t)(n0 + n) * 12 + o] = acc;
    }
}

// ---------------- orchestration (layer-pipelined, interleaved pair state) ----------------
extern "C" void kernel_launch(void* const* d_in, const int* in_sizes, int n_in,
                              void* d_out, int out_size, void* d_ws, size_t ws_size,
                              hipStream_t stream) {
    const float* x   = (const float*)d_in[0];
    const int*   ei  = (const int*)d_in[1];
    const float* ew  = (const float*)d_in[2];
    const float* w1z = (const float*)d_in[3];  const float* b1z = (const float*)d_in[4];
    const float* w1r = (const float*)d_in[5];  const float* b1r = (const float*)d_in[6];
    const float* w1h = (const float*)d_in[7];  const float* b1h = (const float*)d_in[8];
    const float* w2z = (const float*)d_in[9];  const float* b2z = (const float*)d_in[10];
    const float* w2r = (const float*)d_in[11]; const float* b2r = (const float*)d_in[12];
    const float* w2h = (const float*)d_in[13]; const float* b2h = (const float*)d_in[14];
    const float* lw  = (const float*)d_in[15]; const float* lb  = (const float*)d_in[16];
    float* out = (float*)d_out;
    float* ws  = (float*)d_ws;
    if (ws_size < WS_FLOATS * sizeof(float)) return;

    const int EHB = (EHALF + 255) / 256;
    k_zero<<<1024, 256, 0, stream>>>(ws);
    k_hist<<<EHB, 256, 0, stream>>>(ei, ws, 0);
    k_hist<<<EHB, 256, 0, stream>>>(ei, ws, EHALF);
    k_scanA<<<NBLK, 256, 0, stream>>>(ws);
    k_scanB<<<1, 256, 0, stream>>>(ws);
    k_scanC<<<NBLK, 256, 0, stream>>>(ws);
    k_scatter<<<EHB, 256, 0, stream>>>(ei, ew, ws, 0);
    k_scatter<<<EHB, 256, 0, stream>>>(ei, ew, ws, EHALF);
    k_norm<<<NN / 4, 256, 0, stream>>>(ws);
    k_aggx<<<NN / 8, 256, 0, stream>>>(x, ws);
    k_packall<<<437, 256, 0, stream>>>(w1z, w1r, w1h, w2z, w2r, w2h, ws);

    h16* pEven = (h16*)(ws + O_PX0); // pairX_t, t even: [h1(t) | h2(t-1)]
    h16* pOdd  = (h16*)(ws + O_PX1); // pairX_t, t odd
    h16* pzr   = (h16*)(ws + O_PZR); // [rhh1 | rhh2]
    h16* z1    = (h16*)(ws + O_Z1);
    h16* z2    = (h16*)(ws + O_Z2);
    h16* txA = (h16*)(ws + O_TXA);
    h16* txB = (h16*)(ws + O_TXB);
    const float* txx = ws + O_TXX;
    const h16* wf1zr = (const h16*)(ws + O_WF1ZR);
    const h16* wf1h  = (const h16*)(ws + O_WF1H);
    const h16* wf2zr = (const h16*)(ws + O_WF2ZR);
    const h16* wf2h  = (const h16*)(ws + O_WF2H);
    const float* wx1zr = ws + O_WX1ZR;
    const float* wx1h  = ws + O_WX1H;
    const int GAP = NN / 16;        // 3125 dual-gather blocks
    const int GA1 = (NN + 31) / 32; // 1563 single-gather blocks

    auto s1zr = [&](h16* px) -> Seg {
        return {{px, txB, txB, nullptr, nullptr, nullptr}, {128, 256, 256, 0, 0, 0}, {0, 0, 128, 0, 0, 0}};
    };
    Seg s1h = {{pzr, txA, txA, nullptr, nullptr, nullptr}, {128, 128, 128, 0, 0, 0}, {0, 0, 64, 0, 0, 0}};
    auto s2zr = [&](h16* px) -> Seg {
        return {{px, px, txB, txB, txB, txB}, {128, 128, 256, 256, 256, 256}, {0, 64, 0, 64, 128, 192}};
    };
    auto s2h = [&](h16* px) -> Seg {
        return {{px, pzr, txB, txB, txB, txB}, {128, 128, 256, 256, 256, 256}, {0, 64, 0, 64, 128, 192}};
    };

    // ---- prologue (t=0, closed-form: all t=0 L1 A-operands are zero) ----
    k_l1zr0<<<NN / 4, 256, 0, stream>>>(x, txx, wx1zr, b1z, ws);
    k_l1h0<<<NN / 4, 256, 0, stream>>>(x, txx, wx1h, b1h, ws);
    k_aggP<<<GAP, 256, 0, stream>>>(pEven, txB, 256, 0, 128, txB, 256, 64, 192, ws);

    // ---- steady: L2 at t, L1 at t+1 (t = 0..10) ----
    for (int t = 0; t < TT - 1; ++t) {
        h16* pxT  = (t & 1) ? pOdd : pEven;  // pairX_t
        h16* pxT1 = (t & 1) ? pEven : pOdd;  // pairX_{t+1}
        k_mmzr2<<<RB32 * 2, 256, 0, stream>>>(s2zr(pxT), s1zr(pxT), wf2zr, wf1zr, wx1zr,
            x, txx, t + 1, b2z, b2r, b1z, b1r,
            pxT + 64, z2, pzr + 64,
            pxT,      z1, pzr);
        k_aggP<<<GAP, 256, 0, stream>>>(pzr, txA, 128, 0, 64, txB, 256, 64, 192, ws);
        k_mmh2<<<RB32 * 2, 256, 0, stream>>>(s2h(pxT), s1h, wf2h, wf1h, wx1h,
            x, txx, t + 1, b2h, b1h,
            z2, pxT + 64, pxT1 + 64,
            z1, pxT,      pxT1);
        k_aggP<<<GAP, 256, 0, stream>>>(pxT1, txB, 256, 0, 128, txB, 256, 64, 192, ws);
    }

    // ---- epilogue: L2 at t = 11 (pairX_11 = pOdd) ----
    k_mmg<6, 128, 2, 0, 0><<<RB32, 256, 0, stream>>>(s2zr(pOdd), wf2zr, nullptr, nullptr, nullptr, 0,
        b2z, b2r, pOdd + 64, z2, pzr + 64, nullptr);
    k_agg1<<<GA1, 256, 0, stream>>>(pzr + 64, 128, txB, 256, 64, 192, ws);
    k_mmg<6, 64, 1, 1, 0><<<RB32, 256, 0, stream>>>(s2h(pOdd), wf2h, nullptr, nullptr, nullptr, 0,
        b2h, nullptr, pOdd + 64, z2, nullptr, pEven + 64);
    k_final<<<NN / 16, 256, 0, stream>>>(pEven + 64, lw, lb, out);
}

// Round 14
// 1539.324 us; speedup vs baseline: 1.4022x; 1.0412x over previous
//
#include <hip/hip_runtime.h>

#define NN 50000
#define NE 800000
#define TT 12
#define NBIN (4 * NN)
#define NBLK ((NBIN + 255) / 256)
#define EHALF (NE / 2)

typedef _Float16 h16;
typedef __attribute__((ext_vector_type(2))) _Float16 h16x2;
typedef __attribute__((ext_vector_type(4))) _Float16 h16x4;
typedef __attribute__((ext_vector_type(8))) _Float16 half8;
typedef __attribute__((ext_vector_type(4))) float f32x4;
typedef __attribute__((address_space(3))) h16 as3h16;
typedef __attribute__((address_space(3))) half8 as3half8;

static constexpr size_t alignup(size_t x) { return (x + 255) & ~(size_t)255; }
// workspace layout (float units)
static constexpr size_t O_CNT  = 0;                                   // (NBIN+1) ints
static constexpr size_t O_CUR  = alignup(O_CNT + NBIN + 1);           // NBIN ints (dead; layout kept)
static constexpr size_t O_DEGO = alignup(O_CUR + NBIN);               // NN f
static constexpr size_t O_BSUM = alignup(O_DEGO + NN);                // 1024 ints
static constexpr size_t O_BEXC = O_BSUM + 1024;                       // 1024 ints
static constexpr size_t O_EDG  = alignup(O_BEXC + 1024);              // NE uint2 {src, no|ni h16x2}
static constexpr size_t O_TXX  = alignup(O_EDG + (size_t)NE * 2);     // [T][NN][4] f32 (first NE ints reused as rank[] between k_hist and k_scatter)
static constexpr size_t O_WF1ZR= alignup(O_TXX + (size_t)TT * NN * 4);// 12288 f
static constexpr size_t O_WF1H = alignup(O_WF1ZR + 12288);            // 6144 f
static constexpr size_t O_WF2ZR= alignup(O_WF1H + 6144);              // 24576 f
static constexpr size_t O_WF2H = alignup(O_WF2ZR + 24576);            // 12288 f
static constexpr size_t O_WX1ZR= alignup(O_WF2H + 12288);             // 768 f
static constexpr size_t O_WX1H = alignup(O_WX1ZR + 768);              // 384 f
// interleaved pair state buffers: rows of 128 h16 = [partA(64) | partB(64)]
static constexpr size_t O_PX0  = alignup(O_WX1H + 384);               // pairX even: [h1(t) | h2(t-1)], t even
static constexpr size_t O_PX1  = O_PX0 + (size_t)NN * 64;             // pairX odd
static constexpr size_t O_PZR  = O_PX1 + (size_t)NN * 64;             // [rhh1 | rhh2]
static constexpr size_t O_Z1   = O_PZR + (size_t)NN * 64;             // z1 h16 (stride 64)
static constexpr size_t O_Z2   = O_Z1 + (size_t)NN * 32;              // z2 h16
static constexpr size_t O_TXA  = alignup(O_Z2 + (size_t)NN * 32);     // NN*128 h16
static constexpr size_t O_TXB  = alignup(O_TXA + (size_t)NN * 64);    // NN*256 h16
static constexpr size_t WS_FLOATS = O_TXB + (size_t)NN * 128;

__device__ __forceinline__ float sigm_(float x) { return 1.f / (1.f + __expf(-x)); }
__device__ __forceinline__ float tanh_(float x) { float e = __expf(2.f * x); return 1.f - 2.f / (e + 1.f); }

__device__ __forceinline__ void gld_lds16(const h16* g, as3h16* l) {
    __builtin_amdgcn_global_load_lds(
        (const __attribute__((address_space(1))) void*)g,
        (__attribute__((address_space(3))) void*)l, 16, 0, 0);
}

template <int N>
__device__ __forceinline__ void wait_lgkm0_vm() {
    if constexpr (N == 0)      asm volatile("s_waitcnt lgkmcnt(0) vmcnt(0)" ::: "memory");
    else if constexpr (N == 1) asm volatile("s_waitcnt lgkmcnt(0) vmcnt(1)" ::: "memory");
    else                       asm volatile("s_waitcnt lgkmcnt(0) vmcnt(2)" ::: "memory");
}

// ---------------- preprocessing ----------------

// zero: counters + pEven only (txB/pOdd/txA zeroing is dead: t=0 L1 is closed-form and the
// prologue aggP fully writes txB before first read).
__global__ __launch_bounds__(256) void k_zero(float* ws) {
    size_t i = (size_t)blockIdx.x * 256 + threadIdx.x;
    size_t stride = (size_t)gridDim.x * 256;
    for (size_t p = i; p < O_BSUM + 2048; p += stride) ((int*)ws)[p] = 0;
    for (size_t p = i; p < (size_t)NN * 64; p += stride) ws[O_PX0 + p] = 0.f; // pEven (h2(-1)=0; partA overwritten by k_l1h0)
}

// bin = dest*4 + src_quarter; single scattered atomic per edge, rank stored for atomic-free
// scatter. Half-range split keeps these below the steady-loop kernels in the top-5.
__global__ __launch_bounds__(256) void k_hist(const int* ei, float* ws, int ebase) {
    int e = ebase + blockIdx.x * 256 + threadIdx.x;
    if (e >= NE || e >= ebase + EHALF) return;
    int r = ei[e], c = ei[NE + e];
    int bin = c * 4 + r / 12500;
    int rk = atomicAdd((int*)ws + O_CNT + bin, 1);
    ((int*)ws)[O_TXX + e] = rk; // coalesced; O_TXX not live until k_aggx (which overwrites it fully)
}

__global__ __launch_bounds__(256) void k_scanA(float* ws) {
    __shared__ int sh[256];
    int t = threadIdx.x, i = blockIdx.x * 256 + t;
    int v = (i < NBIN) ? ((int*)ws)[O_CNT + i] : 0;
    sh[t] = v; __syncthreads();
    for (int o = 128; o > 0; o >>= 1) { if (t < o) sh[t] += sh[t + o]; __syncthreads(); }
    if (t == 0) ((int*)ws)[O_BSUM + blockIdx.x] = sh[0];
}

__global__ __launch_bounds__(256) void k_scanB(float* ws) {
    __shared__ int tot[256];
    int t = threadIdx.x;
    int* bsum = (int*)ws + O_BSUM;
    int* bexc = (int*)ws + O_BEXC;
    int base = t * 4;
    int v0 = (base + 0 < NBLK) ? bsum[base + 0] : 0;
    int v1 = (base + 1 < NBLK) ? bsum[base + 1] : 0;
    int v2 = (base + 2 < NBLK) ? bsum[base + 2] : 0;
    int v3 = (base + 3 < NBLK) ? bsum[base + 3] : 0;
    int sum = v0 + v1 + v2 + v3;
    tot[t] = sum; __syncthreads();
    for (int o = 1; o < 256; o <<= 1) {
        int a = (t >= o) ? tot[t - o] : 0;
        __syncthreads(); tot[t] += a; __syncthreads();
    }
    int excl = tot[t] - sum;
    if (base + 0 < NBLK) bexc[base + 0] = excl;
    if (base + 1 < NBLK) bexc[base + 1] = excl + v0;
    if (base + 2 < NBLK) bexc[base + 2] = excl + v0 + v1;
    if (base + 3 < NBLK) bexc[base + 3] = excl + v0 + v1 + v2;
    if (t == 255) ((int*)ws)[O_CNT + NBIN] = tot[255];
}

__global__ __launch_bounds__(256) void k_scanC(float* ws) {
    __shared__ int sh[256];
    int t = threadIdx.x, b = blockIdx.x, i = b * 256 + t;
    int v = (i < NBIN) ? ((int*)ws)[O_CNT + i] : 0;
    sh[t] = v; __syncthreads();
    for (int o = 1; o < 256; o <<= 1) {
        int a = (t >= o) ? sh[t - o] : 0;
        __syncthreads(); sh[t] += a; __syncthreads();
    }
    if (i < NBIN) ((int*)ws)[O_CNT + i] = ((int*)ws)[O_BEXC + b] + sh[t] - v;
}

// slot = offs[bin] + precomputed rank (no atomic); dego atomic lives here. Half-range split.
__global__ __launch_bounds__(256) void k_scatter(const int* ei, const float* ew, float* ws, int ebase) {
    int e = ebase + blockIdx.x * 256 + threadIdx.x;
    if (e >= NE || e >= ebase + EHALF) return;
    int r = ei[e], c = ei[NE + e];
    float w = ew[e];
    atomicAdd(ws + O_DEGO + r, w);
    int bin = c * 4 + r / 12500;
    int p = ((const int*)ws)[O_CNT + bin] + ((const int*)ws)[O_TXX + e];
    uint2 rec; rec.x = (unsigned)r; rec.y = __float_as_uint(w);
    ((uint2*)(ws + O_EDG))[p] = rec;
}

// per-node: deg_in = segment sum of w; rewrite records {src, (no,ni) h16x2}
__global__ __launch_bounds__(256) void k_norm(float* ws) {
    int n = blockIdx.x * 4 + (threadIdx.x >> 6);
    int lane = threadIdx.x & 63;
    const int* offs = (const int*)ws + O_CNT;
    uint2* recs = (uint2*)(ws + O_EDG);
    const float* dego = ws + O_DEGO;
    int e0 = offs[4 * n], e1 = offs[4 * n + 4];
    float s = 0.f;
    for (int e = e0 + lane; e < e1; e += 64) s += __uint_as_float(recs[e].y);
    #pragma unroll
    for (int m = 1; m < 64; m <<= 1) s += __shfl_xor(s, m);
    float inv = 1.f / s;
    for (int e = e0 + lane; e < e1; e += 64) {
        uint2 r = recs[e];
        float w = __uint_as_float(r.y);
        h16x2 nv; nv.x = (h16)(w / dego[r.x]); nv.y = (h16)(w * inv);
        r.y = __builtin_bit_cast(unsigned int, nv);
        recs[e] = r;
    }
}

// x aggregation for ALL timesteps, 2 nodes/wave: txx[t][n][c]
__global__ __launch_bounds__(256) void k_aggx(const float* __restrict__ x, float* __restrict__ ws) {
    int tid = threadIdx.x;
    int n = blockIdx.x * 8 + (tid >> 5);
    int l = tid & 31;
    const int* offs = (const int*)ws + O_CNT;
    const uint2* recs = (const uint2*)(ws + O_EDG);
    int e0 = offs[4 * n], e1 = offs[4 * n + 4];
    int f = l / 12, tt2 = l % 12;
    bool act = l < 24;
    float ao = 0.f, ai = 0.f;
    uint2 rc0, rc1;
    if (e0 < e1) {
        rc0 = recs[e0];
        rc1 = recs[(e0 + 1 < e1) ? e0 + 1 : e1 - 1];
    }
    for (int e = e0; e < e1; e += 2) {
        uint2 c0 = rc0, c1 = rc1;
        int n2 = (e + 2 < e1) ? e + 2 : e1 - 1, n3 = (e + 3 < e1) ? e + 3 : e1 - 1;
        rc0 = recs[n2]; rc1 = recs[n3];
        h16x2 nv0 = __builtin_bit_cast(h16x2, c0.y);
        h16x2 nv1 = __builtin_bit_cast(h16x2, c1.y);
        bool ok1 = (e + 1 < e1);
        float no1 = ok1 ? (float)nv1.x : 0.f, ni1 = ok1 ? (float)nv1.y : 0.f;
        if (act) {
            float v0 = x[(size_t)c0.x * 24 + f * 12 + tt2];
            float v1 = x[(size_t)c1.x * 24 + f * 12 + tt2];
            ao += (float)nv0.x * v0 + no1 * v1;
            ai += (float)nv0.y * v0 + ni1 * v1;
        }
    }
    if (act) {
        ws[O_TXX + ((size_t)tt2 * NN + n) * 4 + f] = ao;
        ws[O_TXX + ((size_t)tt2 * NN + n) * 4 + 2 + f] = ai;
    }
}

// ---------------- weight packing ----------------
__device__ void packf_dev(int L, int NO, const float* wa, const float* wb, h16* Wf, int idx) {
    int C = (L == 1) ? 66 : 128;
    int NT = NO / 16;
    int j = idx & 7, l = (idx >> 3) & 63;
    int rest = idx >> 9;
    int ct = rest % NT, ks = rest / NT;
    int k = ks * 32 + ((l >> 4) << 3) + j;
    int col = ct * 16 + (l & 15);
    const float* w = wa; int jj = col;
    if (NO == 128 && col >= 64) { w = wb; jj = col - 64; }
    int G = k >> 6, c6 = k & 63, sg, crow;
    if (L == 1) { sg = G; crow = 2 + c6; }
    else        { sg = G >> 1; crow = ((G & 1) << 6) + c6; }
    float v;
    if (sg == 0)      v = w[(size_t)(0 * C + crow) * 64 + jj] + w[(size_t)(2 * C + crow) * 64 + jj];
    else if (sg == 1) v = w[(size_t)(1 * C + crow) * 64 + jj];
    else              v = w[(size_t)(3 * C + crow) * 64 + jj];
    Wf[idx] = (h16)v;
}

__device__ void packx_dev(int NO, const float* wa, const float* wb, float* Wx, int idx) {
    if (idx >= 6 * NO) return;
    int cc = idx / NO, col = idx % NO;
    const float* w = wa; int jj = col;
    if (NO == 128 && col >= 64) { w = wb; jj = col - 64; }
    int sg = cc >> 1, c = cc & 1;
    float v;
    if (sg == 0)      v = w[(size_t)(0 * 66 + c) * 64 + jj] + w[(size_t)(2 * 66 + c) * 64 + jj];
    else if (sg == 1) v = w[(size_t)(1 * 66 + c) * 64 + jj];
    else              v = w[(size_t)(3 * 66 + c) * 64 + jj];
    Wx[idx] = v;
}

__global__ __launch_bounds__(256) void k_packall(const float* w1z, const float* w1r, const float* w1h,
    const float* w2z, const float* w2r, const float* w2h, float* ws) {
    int b = blockIdx.x, t = threadIdx.x;
    if (b < 96)       packf_dev(1, 128, w1z, w1r, (h16*)(ws + O_WF1ZR), b * 256 + t);
    else if (b < 144) packf_dev(1, 64,  w1h, nullptr, (h16*)(ws + O_WF1H), (b - 96) * 256 + t);
    else if (b < 336) packf_dev(2, 128, w2z, w2r, (h16*)(ws + O_WF2ZR), (b - 144) * 256 + t);
    else if (b < 432) packf_dev(2, 64,  w2h, nullptr, (h16*)(ws + O_WF2H), (b - 336) * 256 + t);
    else {
        int idx = (b - 432) * 256 + t;
        if (idx < 768) packx_dev(128, w1z, w1r, ws + O_WX1ZR, idx);
        int idx2 = idx - 768;
        if (idx2 >= 0 && idx2 < 384) packx_dev(64, w1h, nullptr, ws + O_WX1H, idx2);
    }
}

// ---------------- t=0 closed-form prologue (A-operands identically zero at t=0) ----------------
__global__ __launch_bounds__(256) void k_l1zr0(const float* __restrict__ x, const float* __restrict__ txx,
    const float* __restrict__ wx, const float* __restrict__ bz, float* ws) {
    int tid = threadIdx.x;
    int n = blockIdx.x * 4 + (tid >> 6), col = tid & 63;
    float xa0 = x[(size_t)n * 24], xa1 = x[(size_t)n * 24 + 12];
    float4 tg = *(const float4*)&txx[(size_t)n * 4];
    float v = bz[col] + xa0 * wx[col] + xa1 * wx[128 + col] + tg.x * wx[256 + col]
            + tg.y * wx[384 + col] + tg.z * wx[512 + col] + tg.w * wx[640 + col];
    ((h16*)(ws + O_Z1))[(size_t)n * 64 + col] = (h16)sigm_(v);
}

__global__ __launch_bounds__(256) void k_l1h0(const float* __restrict__ x, const float* __restrict__ txx,
    const float* __restrict__ wx, const float* __restrict__ bh, float* ws) {
    int tid = threadIdx.x;
    int n = blockIdx.x * 4 + (tid >> 6), col = tid & 63;
    float xa0 = x[(size_t)n * 24], xa1 = x[(size_t)n * 24 + 12];
    float4 tg = *(const float4*)&txx[(size_t)n * 4];
    float v = bh[col] + xa0 * wx[col] + xa1 * wx[64 + col] + tg.x * wx[128 + col]
            + tg.y * wx[192 + col] + tg.z * wx[256 + col] + tg.w * wx[320 + col];
    float z = (float)((const h16*)(ws + O_Z1))[(size_t)n * 64 + col];
    float hn = fmaxf((1.f - z) * tanh_(v), 0.f);
    ((h16*)(ws + O_PX0))[(size_t)n * 128 + col] = (h16)hn;
}

// ---- dual gather over interleaved pair table: 4 nodes/wave, 16 lanes x 16B = 256B row, 4-edge unroll ----
__global__ __launch_bounds__(256) void k_aggP(
    const h16* __restrict__ T,
    h16* __restrict__ outA, int orsA, int oA, int iA,
    h16* __restrict__ outB, int orsB, int oB, int iB,
    const float* __restrict__ ws) {
    int tid = threadIdx.x, lane = tid & 63, wv = tid >> 6;
    int q = lane >> 4, fl = lane & 15;
    int n = blockIdx.x * 16 + wv * 4 + q;
    const int* offs = (const int*)ws + O_CNT;
    const uint2* recs = (const uint2*)(ws + O_EDG);
    int e0 = offs[4 * n], e1 = offs[4 * n + 4];
    float ao[8] = {}, ai[8] = {};
    for (int e = e0; e < e1; e += 4) {
        int i1 = e + 1 < e1 ? e + 1 : e1 - 1;
        int i2 = e + 2 < e1 ? e + 2 : e1 - 1;
        int i3 = e + 3 < e1 ? e + 3 : e1 - 1;
        uint2 r0 = recs[e], r1 = recs[i1], r2 = recs[i2], r3 = recs[i3];
        half8 v0 = *(const half8*)(T + (size_t)r0.x * 128 + fl * 8);
        half8 v1 = *(const half8*)(T + (size_t)r1.x * 128 + fl * 8);
        half8 v2 = *(const half8*)(T + (size_t)r2.x * 128 + fl * 8);
        half8 v3 = *(const half8*)(T + (size_t)r3.x * 128 + fl * 8);
        h16x2 m0 = __builtin_bit_cast(h16x2, r0.y);
        h16x2 m1 = __builtin_bit_cast(h16x2, r1.y);
        h16x2 m2 = __builtin_bit_cast(h16x2, r2.y);
        h16x2 m3 = __builtin_bit_cast(h16x2, r3.y);
        float no0 = (float)m0.x, ni0 = (float)m0.y;
        float no1 = (e + 1 < e1) ? (float)m1.x : 0.f, ni1 = (e + 1 < e1) ? (float)m1.y : 0.f;
        float no2 = (e + 2 < e1) ? (float)m2.x : 0.f, ni2 = (e + 2 < e1) ? (float)m2.y : 0.f;
        float no3 = (e + 3 < e1) ? (float)m3.x : 0.f, ni3 = (e + 3 < e1) ? (float)m3.y : 0.f;
        #pragma unroll
        for (int j = 0; j < 8; ++j) {
            float f0 = (float)v0[j], f1 = (float)v1[j], f2 = (float)v2[j], f3 = (float)v3[j];
            ao[j] += no0 * f0 + no1 * f1 + no2 * f2 + no3 * f3;
            ai[j] += ni0 * f0 + ni1 * f1 + ni2 * f2 + ni3 * f3;
        }
    }
    h16* outP = (fl < 8) ? outA : outB;
    int ors = (fl < 8) ? orsA : orsB;
    int fo = (fl < 8) ? fl : fl - 8;
    int oT = ((fl < 8) ? oA : oB) + fo * 8;
    int iT = ((fl < 8) ? iA : iB) + fo * 8;
    half8 wo, wi;
    #pragma unroll
    for (int j = 0; j < 8; ++j) { wo[j] = (h16)ao[j]; wi[j] = (h16)ai[j]; }
    *(half8*)(outP + (size_t)n * ors + oT) = wo;
    *(half8*)(outP + (size_t)n * ors + iT) = wi;
}

// ---- single-table gather (stride hs rows): 8 nodes/wave, 8 lanes x 16B ----
__global__ __launch_bounds__(256) void k_agg1(
    const h16* __restrict__ T, int hs,
    h16* __restrict__ out, int ors, int oA, int iA,
    const float* __restrict__ ws) {
    int tid = threadIdx.x, lane = tid & 63, wv = tid >> 6;
    int q = lane >> 3, fl = lane & 7;
    int n = blockIdx.x * 32 + wv * 8 + q;
    if (n >= NN) n = NN - 1;
    const int* offs = (const int*)ws + O_CNT;
    const uint2* recs = (const uint2*)(ws + O_EDG);
    int e0 = offs[4 * n], e1 = offs[4 * n + 4];
    float ao[8] = {}, ai[8] = {};
    for (int e = e0; e < e1; e += 2) {
        int i1 = e + 1 < e1 ? e + 1 : e1 - 1;
        uint2 r0 = recs[e], r1 = recs[i1];
        half8 v0 = *(const half8*)(T + (size_t)r0.x * hs + fl * 8);
        half8 v1 = *(const half8*)(T + (size_t)r1.x * hs + fl * 8);
        h16x2 m0 = __builtin_bit_cast(h16x2, r0.y);
        h16x2 m1 = __builtin_bit_cast(h16x2, r1.y);
        float no0 = (float)m0.x, ni0 = (float)m0.y;
        float no1 = (e + 1 < e1) ? (float)m1.x : 0.f, ni1 = (e + 1 < e1) ? (float)m1.y : 0.f;
        #pragma unroll
        for (int j = 0; j < 8; ++j) {
            float f0 = (float)v0[j], f1 = (float)v1[j];
            ao[j] += no0 * f0 + no1 * f1;
            ai[j] += ni0 * f0 + ni1 * f1;
        }
    }
    half8 wo, wi;
    #pragma unroll
    for (int j = 0; j < 8; ++j) { wo[j] = (h16)ao[j]; wi[j] = (h16)ai[j]; }
    *(half8*)(out + (size_t)n * ors + oA + fl * 8) = wo;
    *(half8*)(out + (size_t)n * ors + iA + fl * 8) = wi;
}

// ---------------- MFMA dconv GEMM: 4-wave (256t) blocks, 32-row tiles, 4-slot pipelined LDS A ----------------
// R11-measured-best configuration: half-split grid (A-half then B-half; preserves per-half
// streaming L2 locality — R13's parity interleave cost ~54us), __launch_bounds__(256,4)
// (<=128 VGPR, no spill; R12's (256,8) forced 32-VGPR cap -> scratch catastrophe).
// Per group G (4KB): 4 chunks of 512 h16; wave cq stages chunk cq (s=cq&1 row-half, kk=cq>>1
// k-half); reader af[s] = chunk (kk*2+s) at lane*8. Counted-vmcnt 4-slot pipeline.
struct Seg { const h16* p[6]; int st[6]; int of[6]; };
#define RB32 ((NN + 31) / 32)

template <int G>
__device__ __forceinline__ void stage_g(as3h16* lds, const Seg& seg, int bi, int lane, int cq) {
    int r16 = lane & 15, kg = lane >> 4;
    int gr0 = bi * 32 + (cq & 1) * 16 + r16; if (gr0 >= NN) gr0 = NN - 1;
    gld_lds16(seg.p[G] + (size_t)gr0 * seg.st[G] + seg.of[G] + (cq >> 1) * 32 + kg * 8,
              lds + (G & 3) * 2048 + cq * 512);
}

template <int G, int NG, int CT>
__device__ __forceinline__ void gsteps(as3h16* lds, const Seg& seg, int bi, int lane, int cq,
                                       half8 (&wreg)[NG * 2][CT], f32x4 (&acc)[2][CT]) {
    if constexpr (G < NG) {
        constexpr int OUT = (NG - 1 - G) >= 2 ? 2 : (NG - 1 - G);
        wait_lgkm0_vm<OUT>();            // own stage of group G retired; newer stages stay in flight
        __builtin_amdgcn_s_barrier();    // all waves' chunks of G visible; slot (G-1)&3 free
        asm volatile("" ::: "memory");
        if constexpr (G + 3 < NG) stage_g<G + 3>(lds, seg, bi, lane, cq);
        #pragma unroll
        for (int kk = 0; kk < 2; ++kk) {
            half8 af[2];
            #pragma unroll
            for (int s = 0; s < 2; ++s)
                af[s] = *(const as3half8*)(lds + (G & 3) * 2048 + (kk * 2 + s) * 512 + lane * 8);
            #pragma unroll
            for (int c = 0; c < CT; ++c)
                #pragma unroll
                for (int s = 0; s < 2; ++s)
                    acc[s][c] = __builtin_amdgcn_mfma_f32_16x16x32_f16(af[s], wreg[2 * G + kk][c], acc[s][c], 0, 0, 0);
        }
        gsteps<G + 1, NG, CT>(lds, seg, bi, lane, cq, wreg, acc);
    }
}

template <int NG, int NO, int CT, int EPI, int XEPI>
__device__ __forceinline__ void mmg_body(int bi, const Seg& seg, const h16* __restrict__ Wf,
    const float* __restrict__ Wx, const float* __restrict__ x, const float* __restrict__ txx, int t,
    const float* __restrict__ Ba, const float* __restrict__ Bb,
    const h16* Hprev, h16* zbuf, h16* rhh, h16* houth, as3h16* lds) {
    constexpr int KS = NG * 2;
    constexpr int NT = NO / 16;
    int tid = threadIdx.x, lane = tid & 63, cq = tid >> 6; // 4 waves; cq = col quarter & stage chunk
    int ctb = cq * CT;
    int r16 = lane & 15;
    int rg4 = (lane >> 4) * 4;

    half8 wreg[KS][CT];
    #pragma unroll
    for (int ks = 0; ks < KS; ++ks)
        #pragma unroll
        for (int c = 0; c < CT; ++c)
            wreg[ks][c] = *(const half8*)(Wf + (((size_t)ks * NT + ctb + c) * 64 + lane) * 8);

    stage_g<0>(lds, seg, bi, lane, cq);
    stage_g<1>(lds, seg, bi, lane, cq);
    stage_g<2>(lds, seg, bi, lane, cq);

    f32x4 acc[2][CT];
    #pragma unroll
    for (int s = 0; s < 2; ++s)
        #pragma unroll
        for (int c = 0; c < CT; ++c) acc[s][c] = (f32x4){0.f, 0.f, 0.f, 0.f};

    gsteps<0, NG, CT>(lds, seg, bi, lane, cq, wreg, acc);

    int row0 = bi * 32;
    #pragma unroll
    for (int s = 0; s < 2; ++s) {
        int rbase = row0 + s * 16 + rg4;
        float xa0[4], xa1[4]; float4 tg[4];
        if (XEPI) {
            #pragma unroll
            for (int r = 0; r < 4; ++r) {
                int row = rbase + r; if (row >= NN) row = NN - 1;
                xa0[r] = x[(size_t)row * 24 + t];
                xa1[r] = x[(size_t)row * 24 + 12 + t];
                tg[r] = *(const float4*)&txx[((size_t)t * NN + row) * 4];
            }
        }
        #pragma unroll
        for (int c = 0; c < CT; ++c) {
            int col = (ctb + c) * 16 + r16;
            float w0, w1, w2, w3, w4, w5;
            if (XEPI) {
                w0 = Wx[col]; w1 = Wx[NO + col]; w2 = Wx[2 * NO + col];
                w3 = Wx[3 * NO + col]; w4 = Wx[4 * NO + col]; w5 = Wx[5 * NO + col];
            }
            float bb = (EPI == 0) ? (col < 64 ? Ba[col] : Bb[col - 64]) : Ba[col];
            #pragma unroll
            for (int r = 0; r < 4; ++r) {
                int row = rbase + r;
                if (row >= NN) continue;
                float v = acc[s][c][r] + bb;
                if (XEPI) v += xa0[r] * w0 + xa1[r] * w1 + tg[r].x * w2 + tg[r].y * w3 + tg[r].z * w4 + tg[r].w * w5;
                if (EPI == 0) {
                    if (col < 64) zbuf[(size_t)row * 64 + col] = (h16)sigm_(v);
                    else {
                        float rr_ = sigm_(v);
                        float hp = (float)Hprev[(size_t)row * 128 + col - 64];
                        rhh[(size_t)row * 128 + col - 64] = (h16)(rr_ * hp);
                    }
                } else {
                    float ht = tanh_(v);
                    float z = (float)zbuf[(size_t)row * 64 + col];
                    float hp = (float)Hprev[(size_t)row * 128 + col];
                    float hn = fmaxf(z * hp + (1.f - z) * ht, 0.f);
                    houth[(size_t)row * 128 + col] = (h16)hn;
                }
            }
        }
    }
}

template <int NG, int NO, int CT, int EPI, int XEPI>
__global__ __launch_bounds__(256, 4) void k_mmg(Seg seg, const h16* __restrict__ Wf,
    const float* __restrict__ Wx, const float* __restrict__ x, const float* __restrict__ txx, int t,
    const float* __restrict__ Ba, const float* __restrict__ Bb,
    const h16* Hprev, h16* zbuf, h16* rhh, h16* houth) {
    __shared__ __align__(16) h16 smem[4 * 2048];
    mmg_body<NG, NO, CT, EPI, XEPI>(blockIdx.x, seg, Wf, Wx, x, txx, t, Ba, Bb, Hprev, zbuf, rhh, houth,
                                    (as3h16*)smem);
}

// fused ZR pair: blocks [0, RB32) = L2ZR(t); [RB32, RB32*2) = L1ZR(t+1)
__global__ __launch_bounds__(256, 4) void k_mmzr2(Seg sA, Seg sB,
    const h16* __restrict__ wfA, const h16* __restrict__ wfB, const float* __restrict__ wxB,
    const float* __restrict__ x, const float* __restrict__ txx, int tB,
    const float* __restrict__ bAz, const float* __restrict__ bAr,
    const float* __restrict__ bBz, const float* __restrict__ bBr,
    const h16* hpA, h16* zA, h16* rhA,
    const h16* hpB, h16* zB, h16* rhB) {
    __shared__ __align__(16) h16 smem[4 * 2048];
    if (blockIdx.x < RB32)
        mmg_body<6, 128, 2, 0, 0>(blockIdx.x, sA, wfA, nullptr, nullptr, nullptr, 0, bAz, bAr,
                                  hpA, zA, rhA, nullptr, (as3h16*)smem);
    else
        mmg_body<3, 128, 2, 0, 1>(blockIdx.x - RB32, sB, wfB, wxB, x, txx, tB, bBz, bBr,
                                  hpB, zB, rhB, nullptr, (as3h16*)smem);
}

// fused H pair: blocks [0, RB32) = L2H(t); [RB32, RB32*2) = L1H(t+1)
__global__ __launch_bounds__(256, 4) void k_mmh2(Seg sA, Seg sB,
    const h16* __restrict__ wfA, const h16* __restrict__ wfB, const float* __restrict__ wxB,
    const float* __restrict__ x, const float* __restrict__ txx, int tB,
    const float* __restrict__ bAh, const float* __restrict__ bBh,
    h16* zA, const h16* hpA, h16* hoA,
    h16* zB, const h16* hpB, h16* hoB) {
    __shared__ __align__(16) h16 smem[4 * 2048];
    if (blockIdx.x < RB32)
        mmg_body<6, 64, 1, 1, 0>(blockIdx.x, sA, wfA, nullptr, nullptr, nullptr, 0, bAh, nullptr,
                                 hpA, zA, nullptr, hoA, (as3h16*)smem);
    else
        mmg_body<3, 64, 1, 1, 1>(blockIdx.x - RB32, sB, wfB, wxB, x, txx, tB, bBh, nullptr,
                                 hpB, zB, nullptr, hoB, (as3h16*)smem);
}

// ---------------- final projection (pair-strided h2 input) ----------------
__global__ __launch_bounds__(256) void k_final(const h16* __restrict__ h2p, const float* __restrict__ lw,
                                               const float* __restrict__ lb, float* __restrict__ out) {
    __shared__ float sh[16 * 65];
    int t = threadIdx.x;
    int n0 = blockIdx.x * 16;
    int idx = t * 4;
    int nl = idx >> 6, h = idx & 63;
    h16x4 v = *(const h16x4*)&h2p[(size_t)(n0 + nl) * 128 + h];
    sh[nl * 65 + h] = (float)v[0]; sh[nl * 65 + h + 1] = (float)v[1];
    sh[nl * 65 + h + 2] = (float)v[2]; sh[nl * 65 + h + 3] = (float)v[3];
    __syncthreads();
    if (t < 192) {
        int n = t / 12, o = t % 12;
        float acc = lb[o];
        #pragma unroll 8
        for (int k = 0; k < 64; ++k) acc += sh[n * 65 + k] * lw[k * 12 + o];
        out[(size_t)(n0 + n) * 12 + o] = acc;
    }
}

// ---------------- orchestration (layer-pipelined, interleaved pair state) ----------------
extern "C" void kernel_launch(void* const* d_in, const int* in_sizes, int n_in,
                              void* d_out, int out_size, void* d_ws, size_t ws_size,
                              hipStream_t stream) {
    const float* x   = (const float*)d_in[0];
    const int*   ei  = (const int*)d_in[1];
    const float* ew  = (const float*)d_in[2];
    const float* w1z = (const float*)d_in[3];  const float* b1z = (const float*)d_in[4];
    const float* w1r = (const float*)d_in[5];  const float* b1r = (const float*)d_in[6];
    const float* w1h = (const float*)d_in[7];  const float* b1h = (const float*)d_in[8];
    const float* w2z = (const float*)d_in[9];  const float* b2z = (const float*)d_in[10];
    const float* w2r = (const float*)d_in[11]; const float* b2r = (const float*)d_in[12];
    const float* w2h = (const float*)d_in[13]; const float* b2h = (const float*)d_in[14];
    const float* lw  = (const float*)d_in[15]; const float* lb  = (const float*)d_in[16];
    float* out = (float*)d_out;
    float* ws  = (float*)d_ws;
    if (ws_size < WS_FLOATS * sizeof(float)) return;

    const int EHB = (EHALF + 255) / 256;
    k_zero<<<1024, 256, 0, stream>>>(ws);
    k_hist<<<EHB, 256, 0, stream>>>(ei, ws, 0);
    k_hist<<<EHB, 256, 0, stream>>>(ei, ws, EHALF);
    k_scanA<<<NBLK, 256, 0, stream>>>(ws);
    k_scanB<<<1, 256, 0, stream>>>(ws);
    k_scanC<<<NBLK, 256, 0, stream>>>(ws);
    k_scatter<<<EHB, 256, 0, stream>>>(ei, ew, ws, 0);
    k_scatter<<<EHB, 256, 0, stream>>>(ei, ew, ws, EHALF);
    k_norm<<<NN / 4, 256, 0, stream>>>(ws);
    k_aggx<<<NN / 8, 256, 0, stream>>>(x, ws);
    k_packall<<<437, 256, 0, stream>>>(w1z, w1r, w1h, w2z, w2r, w2h, ws);

    h16* pEven = (h16*)(ws + O_PX0); // pairX_t, t even: [h1(t) | h2(t-1)]
    h16* pOdd  = (h16*)(ws + O_PX1); // pairX_t, t odd
    h16* pzr   = (h16*)(ws + O_PZR); // [rhh1 | rhh2]
    h16* z1    = (h16*)(ws + O_Z1);
    h16* z2    = (h16*)(ws + O_Z2);
    h16* txA = (h16*)(ws + O_TXA);
    h16* txB = (h16*)(ws + O_TXB);
    const float* txx = ws + O_TXX;
    const h16* wf1zr = (const h16*)(ws + O_WF1ZR);
    const h16* wf1h  = (const h16*)(ws + O_WF1H);
    const h16* wf2zr = (const h16*)(ws + O_WF2ZR);
    const h16* wf2h  = (const h16*)(ws + O_WF2H);
    const float* wx1zr = ws + O_WX1ZR;
    const float* wx1h  = ws + O_WX1H;
    const int GAP = NN / 16;        // 3125 dual-gather blocks
    const int GA1 = (NN + 31) / 32; // 1563 single-gather blocks

    auto s1zr = [&](h16* px) -> Seg {
        return {{px, txB, txB, nullptr, nullptr, nullptr}, {128, 256, 256, 0, 0, 0}, {0, 0, 128, 0, 0, 0}};
    };
    Seg s1h = {{pzr, txA, txA, nullptr, nullptr, nullptr}, {128, 128, 128, 0, 0, 0}, {0, 0, 64, 0, 0, 0}};
    auto s2zr = [&](h16* px) -> Seg {
        return {{px, px, txB, txB, txB, txB}, {128, 128, 256, 256, 256, 256}, {0, 64, 0, 64, 128, 192}};
    };
    auto s2h = [&](h16* px) -> Seg {
        return {{px, pzr, txB, txB, txB, txB}, {128, 128, 256, 256, 256, 256}, {0, 64, 0, 64, 128, 192}};
    };

    // ---- prologue (t=0, closed-form: all t=0 L1 A-operands are zero) ----
    k_l1zr0<<<NN / 4, 256, 0, stream>>>(x, txx, wx1zr, b1z, ws);
    k_l1h0<<<NN / 4, 256, 0, stream>>>(x, txx, wx1h, b1h, ws);
    k_aggP<<<GAP, 256, 0, stream>>>(pEven, txB, 256, 0, 128, txB, 256, 64, 192, ws);

    // ---- steady: L2 at t, L1 at t+1 (t = 0..10) ----
    for (int t = 0; t < TT - 1; ++t) {
        h16* pxT  = (t & 1) ? pOdd : pEven;  // pairX_t
        h16* pxT1 = (t & 1) ? pEven : pOdd;  // pairX_{t+1}
        k_mmzr2<<<RB32 * 2, 256, 0, stream>>>(s2zr(pxT), s1zr(pxT), wf2zr, wf1zr, wx1zr,
            x, txx, t + 1, b2z, b2r, b1z, b1r,
            pxT + 64, z2, pzr + 64,
            pxT,      z1, pzr);
        k_aggP<<<GAP, 256, 0, stream>>>(pzr, txA, 128, 0, 64, txB, 256, 64, 192, ws);
        k_mmh2<<<RB32 * 2, 256, 0, stream>>>(s2h(pxT), s1h, wf2h, wf1h, wx1h,
            x, txx, t + 1, b2h, b1h,
            z2, pxT + 64, pxT1 + 64,
            z1, pxT,      pxT1);
        k_aggP<<<GAP, 256, 0, stream>>>(pxT1, txB, 256, 0, 128, txB, 256, 64, 192, ws);
    }

    // ---- epilogue: L2 at t = 11 (pairX_11 = pOdd) ----
    k_mmg<6, 128, 2, 0, 0><<<RB32, 256, 0, stream>>>(s2zr(pOdd), wf2zr, nullptr, nullptr, nullptr, 0,
        b2z, b2r, pOdd + 64, z2, pzr + 64, nullptr);
    k_agg1<<<GA1, 256, 0, stream>>>(pzr + 64, 128, txB, 256, 64, 192, ws);
    k_mmg<6, 64, 1, 1, 0><<<RB32, 256, 0, stream>>>(s2h(pOdd), wf2h, nullptr, nullptr, nullptr, 0,
        b2h, nullptr, pOdd + 64, z2, nullptr, pEven + 64);
    k_final<<<NN / 16, 256, 0, stream>>>(pEven + 64, lw, lb, out);
}